// Round 4
// baseline (1036.189 us; speedup 1.0000x reference)
//
#include <hip/hip_runtime.h>
#include <math.h>

// SimpleGSLModel: B=8192, D=768, TOP_K=5
// R4: (a) s_topk: XOR-swizzled As/Bs (pre-swizzled global src per m173/rule#21) kills the
//         16-way MFMA-fragment bank conflict; St -> [128][64] swizzled bf16, 2-phase epilogue;
//         Ae dropped from candidate RANKING only (margin ~9 S-units vs needed 1.0; exact
//         blend stays in refine5) -> -268 MB HBM.
//     (b) G sgemm retiled 64x128 (768 blocks = 3/CU) with per-element fmaf chain order
//         preserved exactly -> bitwise-identical G (selection-critical).
//     (c) split-bf16 MLP GEMMs: hi/lo interleaved into one K=2K pass (3 launches not 9).

typedef __attribute__((ext_vector_type(8))) short short8v;
typedef __attribute__((ext_vector_type(4))) float f32x4;

__device__ __forceinline__ unsigned short f2bf(float f) {
  unsigned u = __float_as_uint(f);
  u += 0x7fffu + ((u >> 16) & 1u);   // RNE
  return (unsigned short)(u >> 16);
}
__device__ __forceinline__ float bf2f(unsigned short h) {
  return __uint_as_float(((unsigned)h) << 16);
}
__device__ __forceinline__ float gelu_f(float x) {
  return 0.5f * x * (1.f + erff(x * 0.7071067811865475f));
}
__device__ __forceinline__ void gload16(const void* g, void* l) {
  __builtin_amdgcn_global_load_lds(
      (const __attribute__((address_space(1))) unsigned int*)g,
      (__attribute__((address_space(3))) unsigned int*)l, 16, 0, 0);
}

// sorted-descending insert, static indexing
__device__ __forceinline__ void ins16(float v, int j, float (&lv)[16], int (&li)[16]) {
#pragma unroll
  for (int p = 15; p >= 1; --p) {
    bool shiftv = v > lv[p - 1];
    bool here = (v > lv[p]) && !shiftv;
    float nv = shiftv ? lv[p - 1] : (here ? v : lv[p]);
    int ni = shiftv ? li[p - 1] : (here ? j : li[p]);
    lv[p] = nv; li[p] = ni;
  }
  if (v > lv[0]) { lv[0] = v; li[0] = j; }
}

__global__ __launch_bounds__(256) void cvt_bf16(const float* __restrict__ in,
                                                unsigned short* __restrict__ out, int n4) {
  int t = blockIdx.x * 256 + threadIdx.x;
  if (t >= n4) return;
  float4 f = ((const float4*)in)[t];
  ushort4 r;
  r.x = f2bf(f.x); r.y = f2bf(f.y); r.z = f2bf(f.z); r.w = f2bf(f.w);
  ((ushort4*)out)[t] = r;
}

// f32 [rows][K] -> bf16 hi/lo interleaved [rows][2K] (row = [hi(K) | lo(K)])
__global__ __launch_bounds__(256) void split2(const float* __restrict__ in,
                                              unsigned short* __restrict__ out,
                                              int K, int n4) {
  int t = blockIdx.x * 256 + threadIdx.x;
  if (t >= n4) return;
  int kq = K >> 2;
  int row = t / kq, c4 = t - row * kq;
  float4 f = ((const float4*)in)[t];
  ushort4 h, l;
  float x;
  x = f.x; h.x = f2bf(x); l.x = f2bf(x - bf2f(h.x));
  x = f.y; h.y = f2bf(x); l.y = f2bf(x - bf2f(h.y));
  x = f.z; h.z = f2bf(x); l.z = f2bf(x - bf2f(h.z));
  x = f.w; h.w = f2bf(x); l.w = f2bf(x - bf2f(h.w));
  *(ushort4*)(out + (size_t)row * 2 * K + c4 * 4) = h;
  *(ushort4*)(out + (size_t)row * 2 * K + K + c4 * 4) = l;
}

// W [K x N] f32 -> transposed hi/lo interleaved bf16 [N][2K]
__global__ __launch_bounds__(256) void split_wt2(const float* __restrict__ W,
                                                 unsigned short* __restrict__ t2,
                                                 int K, int N) {
  __shared__ float tile[32][33];
  int kb = blockIdx.x * 32, nb = blockIdx.y * 32;
  int tx = threadIdx.x & 31, ty = threadIdx.x >> 5;
#pragma unroll
  for (int p = 0; p < 4; ++p)
    tile[ty + p * 8][tx] = W[(size_t)(kb + ty + p * 8) * N + nb + tx];
  __syncthreads();
#pragma unroll
  for (int p = 0; p < 4; ++p) {
    int n = ty + p * 8;
    float x = tile[tx][n];
    unsigned short h = f2bf(x);
    unsigned short l = f2bf(x - bf2f(h));
    t2[(size_t)(nb + n) * (2 * K) + kb + tx] = h;
    t2[(size_t)(nb + n) * (2 * K) + K + kb + tx] = l;
  }
}

// -------- fp32 SGEMM for G only. 64x128 tile (768 blocks = 3/CU). Per-element fmaf chain
// order (k ascending, single acc) identical to R1 -> bitwise-identical output. --------
__global__ __launch_bounds__(256) void sgemm_f32(const float* __restrict__ A,
                                                 const float* __restrict__ Bm,
                                                 float* __restrict__ C, int N, int K) {
  __shared__ float As[16][68];
  __shared__ float Bs[16][132];
  const int r0 = blockIdx.x * 64, c0 = blockIdx.y * 128;
  const int tid = threadIdx.x;
  const int tr = tid >> 4, tc = tid & 15;
  float acc[4][8];
#pragma unroll
  for (int i = 0; i < 4; ++i)
#pragma unroll
    for (int j = 0; j < 8; ++j) acc[i][j] = 0.f;

  for (int k0 = 0; k0 < K; k0 += 16) {
    {
      int row = tid >> 2, kq = tid & 3;
      float4 a4 = *(const float4*)(A + (size_t)(r0 + row) * K + k0 + kq * 4);
      As[kq * 4 + 0][row] = a4.x; As[kq * 4 + 1][row] = a4.y;
      As[kq * 4 + 2][row] = a4.z; As[kq * 4 + 3][row] = a4.w;
#pragma unroll
      for (int s = 0; s < 2; ++s) {
        int ch = tid + s * 256;
        int kk = ch >> 5, nq = ch & 31;
        *(float4*)&Bs[kk][nq * 4] = *(const float4*)(Bm + (size_t)(k0 + kk) * N + c0 + nq * 4);
      }
    }
    __syncthreads();
#pragma unroll
    for (int k = 0; k < 16; ++k) {
      float a[4], b[8];
      *(float4*)&a[0] = *(const float4*)&As[k][tr * 4];
      *(float4*)&b[0] = *(const float4*)&Bs[k][tc * 8];
      *(float4*)&b[4] = *(const float4*)&Bs[k][tc * 8 + 4];
#pragma unroll
      for (int i = 0; i < 4; ++i)
#pragma unroll
        for (int j = 0; j < 8; ++j) acc[i][j] = fmaf(a[i], b[j], acc[i][j]);
    }
    __syncthreads();
  }
#pragma unroll
  for (int i = 0; i < 4; ++i) {
    int r = r0 + tr * 4 + i;
#pragma unroll
    for (int jq = 0; jq < 2; ++jq)
      *(float4*)(C + (size_t)r * N + c0 + tc * 8 + jq * 4) = *(float4*)&acc[i][jq * 4];
  }
}

// ---------- bf16 MFMA GEMM, 128x128 tile, swizzled staging (conflict-free frag reads) ------
// A: M x K bf16 row-major; Bt: N x K bf16 row-major; C: M x N f32. EPI: 0=none 1=bias+gelu
template <int EPI>
__global__ __launch_bounds__(256) void gemm_bt(const unsigned short* __restrict__ A,
                                               const unsigned short* __restrict__ Bt,
                                               const float* __restrict__ bias,
                                               float* __restrict__ C, int N, int K) {
  __shared__ __align__(16) unsigned short As[128 * 64];
  __shared__ __align__(16) unsigned short Bs[128 * 64];
  const int r0 = blockIdx.x * 128, c0 = blockIdx.y * 128;
  const int tid = threadIdx.x, lane = tid & 63, w = tid >> 6;
  const int wr = w >> 1, wc = w & 1;
  f32x4 acc[4][4];
  const f32x4 z4 = {0.f, 0.f, 0.f, 0.f};
#pragma unroll
  for (int i = 0; i < 4; ++i)
#pragma unroll
    for (int j = 0; j < 4; ++j) acc[i][j] = z4;

  const int srow = w * 32 + (lane >> 3);
  const int ksl = (lane & 7) ^ (lane >> 3);   // pre-swizzled global k-slot (rule #21 / m173)
  const unsigned short* aSrc = A + (size_t)(r0 + srow) * K + ksl * 8;
  const unsigned short* bSrc = Bt + (size_t)(c0 + srow) * K + ksl * 8;
  const int rsw = (lane & 7);                 // row&7 of every fragment row this lane reads

  for (int k0 = 0; k0 < K; k0 += 64) {
#pragma unroll
    for (int t = 0; t < 4; ++t) {
      gload16(aSrc + k0 + (size_t)t * 8 * K, (char*)As + (w * 32 + t * 8) * 128);
      gload16(bSrc + k0 + (size_t)t * 8 * K, (char*)Bs + (w * 32 + t * 8) * 128);
    }
    __syncthreads();
#pragma unroll
    for (int ks = 0; ks < 2; ++ks) {
      short8v af[4], bf[4];
      const int slot = ((ks * 4 + (lane >> 4)) ^ rsw) << 4;
#pragma unroll
      for (int f = 0; f < 4; ++f) {
        af[f] = *(const short8v*)((const char*)As + (wr * 64 + f * 16 + (lane & 15)) * 128 + slot);
        bf[f] = *(const short8v*)((const char*)Bs + (wc * 64 + f * 16 + (lane & 15)) * 128 + slot);
      }
#pragma unroll
      for (int fi = 0; fi < 4; ++fi)
#pragma unroll
        for (int fj = 0; fj < 4; ++fj)
          acc[fi][fj] = __builtin_amdgcn_mfma_f32_16x16x32_bf16(af[fi], bf[fj], acc[fi][fj], 0, 0, 0);
    }
    __syncthreads();
  }
#pragma unroll
  for (int fi = 0; fi < 4; ++fi)
#pragma unroll
    for (int fj = 0; fj < 4; ++fj) {
      int col = c0 + wc * 64 + fj * 16 + (lane & 15);
      int rowb = r0 + wr * 64 + fi * 16 + (lane >> 4) * 4;
#pragma unroll
      for (int r = 0; r < 4; ++r) {
        size_t idx = (size_t)(rowb + r) * N + col;
        float x = acc[fi][fj][r];
        if constexpr (EPI) x = gelu_f(x + bias[col]);
        C[idx] = x;
      }
    }
}

// ---------- fused S = Gh@Xh^T + per-row approx top-16 by bf16(S) (exact blend in refine5) --
// grid (64 row-blocks, 8 col-chunks of 1024); 256 thr = 4 waves (2x2)
__global__ __launch_bounds__(256) void s_topk(const unsigned short* __restrict__ Gh,
                                              const unsigned short* __restrict__ Xh,
                                              float* __restrict__ pv, int* __restrict__ pix) {
  __shared__ __align__(16) unsigned short As[128 * 64];
  __shared__ __align__(16) unsigned short Bs[128 * 64];
  __shared__ __align__(16) unsigned short St[128 * 64];
  const int r0 = blockIdx.x * 128;
  const int chunk = blockIdx.y;
  const int tid = threadIdx.x, lane = tid & 63, w = tid >> 6;
  const int wr = w >> 1, wc = w & 1;
  float lv[16]; int li[16];
#pragma unroll
  for (int q = 0; q < 16; ++q) { lv[q] = -1e30f; li[q] = 0; }

  const int stgrow = w * 32 + (lane >> 3);
  const int ksl = (lane & 7) ^ (lane >> 3);
  const unsigned short* aSrc = Gh + (size_t)(r0 + stgrow) * 768 + ksl * 8;
  const int rsw = (lane & 7);
  const int srow = tid & 127, sg = tid >> 7;
  const int ssw = (srow & 7) << 4;

  for (int jt = 0; jt < 8; ++jt) {
    const int j0 = chunk * 1024 + jt * 128;
    const unsigned short* bSrc = Xh + (size_t)(j0 + stgrow) * 768 + ksl * 8;
    f32x4 acc[4][4];
    const f32x4 z4 = {0.f, 0.f, 0.f, 0.f};
#pragma unroll
    for (int i = 0; i < 4; ++i)
#pragma unroll
      for (int j = 0; j < 4; ++j) acc[i][j] = z4;

    for (int k0 = 0; k0 < 768; k0 += 64) {
#pragma unroll
      for (int t = 0; t < 4; ++t) {
        gload16(aSrc + k0 + (size_t)t * 8 * 768, (char*)As + (w * 32 + t * 8) * 128);
        gload16(bSrc + k0 + (size_t)t * 8 * 768, (char*)Bs + (w * 32 + t * 8) * 128);
      }
      __syncthreads();
#pragma unroll
      for (int ks = 0; ks < 2; ++ks) {
        short8v af[4], bf[4];
        const int slot = ((ks * 4 + (lane >> 4)) ^ rsw) << 4;
#pragma unroll
        for (int f = 0; f < 4; ++f) {
          af[f] = *(const short8v*)((const char*)As + (wr * 64 + f * 16 + (lane & 15)) * 128 + slot);
          bf[f] = *(const short8v*)((const char*)Bs + (wc * 64 + f * 16 + (lane & 15)) * 128 + slot);
        }
#pragma unroll
        for (int fi = 0; fi < 4; ++fi)
#pragma unroll
          for (int fj = 0; fj < 4; ++fj)
            acc[fi][fj] = __builtin_amdgcn_mfma_f32_16x16x32_bf16(af[fi], bf[fj], acc[fi][fj], 0, 0, 0);
      }
      __syncthreads();
    }
    // two-phase epilogue: cols [h*64, h*64+64) staged to swizzled St[128][64] bf16, scanned
#pragma unroll
    for (int h = 0; h < 2; ++h) {
      if (wc == h) {
#pragma unroll
        for (int fi = 0; fi < 4; ++fi)
#pragma unroll
          for (int fj = 0; fj < 4; ++fj) {
            int colb = fj * 32 + (lane & 15) * 2;
#pragma unroll
            for (int r = 0; r < 4; ++r) {
              int row = wr * 64 + fi * 16 + (lane >> 4) * 4 + r;
              int byo = (row * 128 + colb) ^ ((row & 7) << 4);
              *(unsigned short*)((char*)St + byo) = f2bf(acc[fi][fj][r]);
            }
          }
      }
      __syncthreads();
#pragma unroll
      for (int cb = 0; cb < 4; ++cb) {
        int byo = (srow * 128 + sg * 64 + cb * 16) ^ ssw;
        short8v v8 = *(const short8v*)((const char*)St + byo);
#pragma unroll
        for (int e = 0; e < 8; ++e) {
          float v = bf2f((unsigned short)v8[e]);
          if (v > lv[15]) ins16(v, j0 + h * 64 + sg * 32 + cb * 8 + e, lv, li);
        }
      }
      __syncthreads();
    }
  }
  // merge sg=1 list into sg=0, write per-(row,chunk) partial top-16 (St as f32 scratch: 16KB)
  float* StF = (float*)St;
  if (sg == 1) {
#pragma unroll
    for (int q = 0; q < 16; ++q) {
      StF[srow * 32 + q] = lv[q];
      StF[srow * 32 + 16 + q] = __int_as_float(li[q]);
    }
  }
  __syncthreads();
  if (sg == 0) {
#pragma unroll
    for (int q = 0; q < 16; ++q) {
      float v = StF[srow * 32 + q];
      int j = __float_as_int(StF[srow * 32 + 16 + q]);
      if (v > lv[15]) ins16(v, j, lv, li);
    }
    size_t basep = ((size_t)(r0 + srow) * 8 + chunk) * 16;
#pragma unroll
    for (int q = 0; q < 16; ++q) { pv[basep + q] = lv[q]; pix[basep + q] = li[q]; }
  }
}

__global__ __launch_bounds__(256) void merge16(const float* __restrict__ pv,
                                               const int* __restrict__ pix,
                                               int* __restrict__ gidx) {
  int row = blockIdx.x * 256 + threadIdx.x;
  float lv[16]; int li[16];
#pragma unroll
  for (int q = 0; q < 16; ++q) { lv[q] = -1e30f; li[q] = 0; }
  for (int ch = 0; ch < 8; ++ch) {
    size_t base = ((size_t)row * 8 + ch) * 16;
#pragma unroll
    for (int q = 0; q < 16; ++q) {
      float v = pv[base + q];
      if (v > lv[15]) ins16(v, pix[base + q], lv, li);
    }
  }
#pragma unroll
  for (int q = 0; q < 16; ++q) gidx[row * 16 + q] = li[q];
}

// exact f32 re-evaluation of 16 candidates (incl. Ae blend), exact top-5 (ties -> lower index)
__global__ __launch_bounds__(256) void refine5(const float* __restrict__ G,
                                               const float* __restrict__ X,
                                               const float* __restrict__ Ae,
                                               const int* __restrict__ gidx,
                                               const float* __restrict__ ralpha,
                                               int* __restrict__ t5i, float* __restrict__ t5v) {
  int i = blockIdx.x * 4 + (threadIdx.x >> 6);
  int lane = threadIdx.x & 63;
  int c = lane >> 2, s = lane & 3;
  float sa = 1.f / (1.f + expf(-ralpha[0]));
  int j = gidx[i * 16 + c];
  const float* g = G + (size_t)i * 768;
  const float* x = X + (size_t)j * 768;
  float a = 0.f;
#pragma unroll 8
  for (int t = 0; t < 192; ++t) a = fmaf(g[s + 4 * t], x[s + 4 * t], a);
  a += __shfl_xor(a, 1);
  a += __shfl_xor(a, 2);
  float v = sa * Ae[(size_t)i * 8192 + j] + (1.f - sa) * fmaxf(a, 0.f);
  float vs[16]; int js[16];
#pragma unroll
  for (int q = 0; q < 16; ++q) { vs[q] = __shfl(v, q * 4); js[q] = __shfl(j, q * 4); }
  if (lane == 0) {
    unsigned used = 0;
#pragma unroll
    for (int t = 0; t < 5; ++t) {
      float bv = -1e30f; int bj = 0; int bq = 0; bool any = false;
#pragma unroll
      for (int q = 0; q < 16; ++q) {
        bool ok = ((used >> q) & 1u) == 0u;
        bool better = ok && (!any || vs[q] > bv || (vs[q] == bv && js[q] < bj));
        bv = better ? vs[q] : bv; bj = better ? js[q] : bj; bq = better ? q : bq;
        any = any || better;
      }
      used |= (1u << bq);
      t5v[(size_t)i * 5 + t] = bv;
      t5i[(size_t)i * 5 + t] = bj;
    }
  }
}

// -------- symmetrized sparse-A construction (canonical-pair dedup) --------
__global__ void edge_deg(const int* __restrict__ t5i, int* __restrict__ deg) {
  int e = blockIdx.x * 256 + threadIdx.x;
  if (e >= 40960) return;
  int i = e / 5, t = e - i * 5;
  int j = t5i[i * 5 + t];
  if (j == i) return;
  bool rev = false;
#pragma unroll
  for (int u = 0; u < 5; ++u) rev = rev || (t5i[j * 5 + u] == i);
  if (!rev || i < j) { atomicAdd(&deg[i], 1); atomicAdd(&deg[j], 1); }
}

__global__ void scan8k(const int* __restrict__ deg, int* __restrict__ off) {
  __shared__ int sums[256];
  int tid = threadIdx.x;
  int base = tid * 32;
  int s = 0;
  for (int u = 0; u < 32; ++u) s += deg[base + u];
  sums[tid] = s;
  __syncthreads();
  for (int d = 1; d < 256; d <<= 1) {
    int v = (tid >= d) ? sums[tid - d] : 0;
    __syncthreads();
    sums[tid] += v;
    __syncthreads();
  }
  int run = tid ? sums[tid - 1] : 0;
  for (int u = 0; u < 32; ++u) { off[base + u] = run; run += deg[base + u]; }
  if (tid == 255) off[8192] = run;
}

__global__ __launch_bounds__(256) void edge_fill(const int* __restrict__ t5i,
                                                 const float* __restrict__ t5v,
                                                 const float* __restrict__ G,
                                                 const float* __restrict__ X,
                                                 const float* __restrict__ Ae,
                                                 const float* __restrict__ ralpha,
                                                 const int* __restrict__ off,
                                                 int* __restrict__ cursor,
                                                 int* __restrict__ ccol, float* __restrict__ cval) {
  int e = blockIdx.x * 4 + (threadIdx.x >> 6);
  if (e >= 40960) return;
  int lane = threadIdx.x & 63;
  int i = e / 5, t = e - i * 5;
  int j = t5i[i * 5 + t];
  if (j == i) return;
  int rev = -1;
#pragma unroll
  for (int u = 0; u < 5; ++u)
    if (t5i[j * 5 + u] == i) rev = u;
  if (!(rev < 0 || i < j)) return;
  float vji;
  if (rev >= 0) {
    vji = t5v[j * 5 + rev];
  } else {
    const float* g = G + (size_t)j * 768;
    const float* x = X + (size_t)i * 768;
    float a = 0.f;
#pragma unroll
    for (int u = 0; u < 12; ++u) a = fmaf(g[lane + 64 * u], x[lane + 64 * u], a);
#pragma unroll
    for (int d = 32; d; d >>= 1) a += __shfl_xor(a, d);
    float sa = 1.f / (1.f + expf(-ralpha[0]));
    vji = sa * Ae[(size_t)j * 8192 + i] + (1.f - sa) * fmaxf(a, 0.f);
  }
  if (lane == 0) {
    float vij = t5v[i * 5 + t];
    int p0 = off[i] + atomicAdd(&cursor[i], 1);
    ccol[p0] = j; cval[p0] = vij;
    int p1 = off[j] + atomicAdd(&cursor[j], 1);
    ccol[p1] = i; cval[p1] = vji;
  }
}

// M = D^-1 * (X[i] + sum val * X[j]) ; one block per row
__global__ __launch_bounds__(256) void gather_gcn(const float* __restrict__ X,
                                                  const int* __restrict__ off,
                                                  const int* __restrict__ ccol,
                                                  const float* __restrict__ cval,
                                                  float* __restrict__ M) {
  __shared__ float red[256];
  __shared__ float sdinv;
  int i = blockIdx.x, tid = threadIdx.x;
  int s0 = off[i], cnt = off[i + 1] - s0;
  float s = 0.f;
  for (int e = tid; e < cnt; e += 256) s += cval[s0 + e];
  red[tid] = s;
  __syncthreads();
  for (int d = 128; d; d >>= 1) {
    if (tid < d) red[tid] += red[tid + d];
    __syncthreads();
  }
  if (tid == 0) sdinv = 1.f / fmaxf(1.f + red[0], 1e-8f);
  __syncthreads();
  float dinv = sdinv;
  const float* xi = X + (size_t)i * 768;
  float a0 = xi[tid], a1 = xi[tid + 256], a2 = xi[tid + 512];
  for (int e = 0; e < cnt; ++e) {
    float v = cval[s0 + e];
    const float* xr = X + (size_t)ccol[s0 + e] * 768;
    a0 = fmaf(v, xr[tid], a0);
    a1 = fmaf(v, xr[tid + 256], a1);
    a2 = fmaf(v, xr[tid + 512], a2);
  }
  float* mi = M + (size_t)i * 768;
  mi[tid] = a0 * dinv; mi[tid + 256] = a1 * dinv; mi[tid + 512] = a2 * dinv;
}

__global__ __launch_bounds__(256) void final_head(const float* __restrict__ h2,
                                                  const float* __restrict__ W3,
                                                  const float* __restrict__ b3,
                                                  float* __restrict__ out) {
  int i = blockIdx.x * 4 + (threadIdx.x >> 6);
  int lane = threadIdx.x & 63;
  const float* r = h2 + (size_t)i * 256;
  float s = r[lane] * W3[lane] + r[lane + 64] * W3[lane + 64] +
            r[lane + 128] * W3[lane + 128] + r[lane + 192] * W3[lane + 192];
#pragma unroll
  for (int d = 32; d; d >>= 1) s += __shfl_xor(s, d);
  if (lane == 0) out[i] = s + b3[0];
}

extern "C" void kernel_launch(void* const* d_in, const int* in_sizes, int n_in,
                              void* d_out, int out_size, void* d_ws, size_t ws_size,
                              hipStream_t stream) {
  const float* X   = (const float*)d_in[0];
  const float* Ae  = (const float*)d_in[1];
  const float* Wg  = (const float*)d_in[2];
  const float* ra  = (const float*)d_in[3];
  const float* Wgc = (const float*)d_in[4];
  const float* bgc = (const float*)d_in[5];
  const float* W1  = (const float*)d_in[6];
  const float* b1  = (const float*)d_in[7];
  const float* W2  = (const float*)d_in[8];
  const float* b2  = (const float*)d_in[9];
  const float* W3  = (const float*)d_in[10];
  const float* b3  = (const float*)d_in[11];
  float* out = (float*)d_out;

  char* w = (char*)d_ws;
  size_t off_ = 0;
  auto take = [&](size_t n) -> void* {
    void* p = w + off_;
    off_ += (n + 255) & ~(size_t)255;
    return p;
  };
  float* G            = (float*)take((size_t)8192 * 768 * 4);          // 25.17 MB
  unsigned short* Xh  = (unsigned short*)take((size_t)8192 * 768 * 2); // 12.58
  unsigned short* Gh  = (unsigned short*)take((size_t)8192 * 768 * 2); // 12.58
  float* pv           = (float*)take((size_t)8192 * 128 * 4);          // 4.19
  int* pix            = (int*)take((size_t)8192 * 128 * 4);            // 4.19
  int* gidx           = (int*)take((size_t)8192 * 16 * 4);
  int* t5i            = (int*)take((size_t)8192 * 5 * 4);
  float* t5v          = (float*)take((size_t)8192 * 5 * 4);
  int* deg            = (int*)take((size_t)8192 * 4);
  int* offr           = (int*)take((size_t)8193 * 4);
  int* cur            = (int*)take((size_t)8192 * 4);
  int* ccol           = (int*)take((size_t)81920 * 4);
  float* cval         = (float*)take((size_t)81920 * 4);
  unsigned short* Wc2 = (unsigned short*)take((size_t)768 * 1536 * 2); // 2.36
  unsigned short* W12 = (unsigned short*)take((size_t)512 * 1536 * 2); // 1.57
  unsigned short* W22 = (unsigned short*)take((size_t)256 * 1024 * 2); // 0.52
  // total ~63.5 MB

  // region reuse (stream-ordered):
  // Xh+Gh (25.17 MB, dead after s_topk): Mf -> Hf -> h1f
  float* Mf  = (float*)Xh;
  float* Hf  = (float*)Xh;
  float* h1f = (float*)Xh;
  // G (25.17 MB, dead after edge_fill): interleaved activation planes A2
  unsigned short* A2 = (unsigned short*)G;
  // pv+pix (8.39 MB, dead after merge16): h2
  float* h2f = (float*)pv;

  // 1. G = X @ Wg — bitwise-identical fp32 chain (selection-critical)
  sgemm_f32<<<dim3(128, 6), 256, 0, stream>>>(X, Wg, G, 768, 768);
  // 2. bf16 copies for candidate pass
  cvt_bf16<<<6144, 256, 0, stream>>>(X, Xh, 1572864);
  cvt_bf16<<<6144, 256, 0, stream>>>(G, Gh, 1572864);
  // 3. interleaved weight planes for MLP
  split_wt2<<<dim3(24, 24), 256, 0, stream>>>(Wgc, Wc2, 768, 768);
  split_wt2<<<dim3(24, 16), 256, 0, stream>>>(W1, W12, 768, 512);
  split_wt2<<<dim3(16, 8), 256, 0, stream>>>(W2, W22, 512, 256);

  // 4. fused S + per-row top-16 candidates (ranked by bf16 S; exact blend in refine5)
  s_topk<<<dim3(64, 8), 256, 0, stream>>>(Gh, Xh, pv, pix);
  merge16<<<32, 256, 0, stream>>>(pv, pix, gidx);
  refine5<<<2048, 256, 0, stream>>>(G, X, Ae, gidx, ra, t5i, t5v);

  // 5. sparse symmetric A as CSR
  hipMemsetAsync(deg, 0, 8192 * 4, stream);
  hipMemsetAsync(cur, 0, 8192 * 4, stream);
  edge_deg<<<160, 256, 0, stream>>>(t5i, deg);
  scan8k<<<1, 256, 0, stream>>>(deg, offr);
  edge_fill<<<10240, 256, 0, stream>>>(t5i, t5v, G, X, Ae, ra, offr, cur, ccol, cval);

  // 6. M = A_norm @ X   (into Xh+Gh region)
  gather_gcn<<<8192, 256, 0, stream>>>(X, offr, ccol, cval, Mf);

  // 7. H = gelu(M @ Wgcn + bgc) — one split-bf16 pass, K=1536
  split2<<<6144, 256, 0, stream>>>(Mf, A2, 768, 1572864);
  gemm_bt<1><<<dim3(64, 6), 256, 0, stream>>>(A2, Wc2, bgc, Hf, 768, 1536);

  // 8. h1 = gelu(H @ W1 + b1)
  split2<<<6144, 256, 0, stream>>>(Hf, A2, 768, 1572864);
  gemm_bt<1><<<dim3(64, 4), 256, 0, stream>>>(A2, W12, b1, h1f, 512, 1536);

  // 9. h2 = gelu(h1 @ W2 + b2)
  split2<<<4096, 256, 0, stream>>>(h1f, A2, 512, 1048576);
  gemm_bt<1><<<dim3(64, 2), 256, 0, stream>>>(A2, W22, b2, h2f, 256, 1024);

  // 10. out = h2 @ W3 + b3
  final_head<<<2048, 256, 0, stream>>>(h2f, W3, b3, out);

  (void)in_sizes; (void)n_in; (void)out_size; (void)ws_size;
}

// Round 5
// 721.673 us; speedup vs baseline: 1.4358x; 1.4358x over previous
//
#include <hip/hip_runtime.h>
#include <math.h>

// SimpleGSLModel: B=8192, D=768, TOP_K=5
// R5: s_topk rebuilt for occupancy: 512 thr / 8 waves, wave-tile 64x32 (acc[4][2]=32 VGPR),
//     single-phase St epilogue (acc dead before scan), St[128][128] bf16 swizzled (32KB),
//     LDS 64KB -> 2 blocks/CU (16 waves/CU). Scan: per-thread 32-col quarter, top-8 lists
//     (32 lists/row merged in merge16 -> top-16 for exact refine5). K-loop swizzle kept (R4).
//     G sgemm / MLP gemm_bt / sparse phase: R4-verbatim (passed).

typedef __attribute__((ext_vector_type(8))) short short8v;
typedef __attribute__((ext_vector_type(4))) float f32x4;

__device__ __forceinline__ unsigned short f2bf(float f) {
  unsigned u = __float_as_uint(f);
  u += 0x7fffu + ((u >> 16) & 1u);   // RNE
  return (unsigned short)(u >> 16);
}
__device__ __forceinline__ float bf2f(unsigned short h) {
  return __uint_as_float(((unsigned)h) << 16);
}
__device__ __forceinline__ float gelu_f(float x) {
  return 0.5f * x * (1.f + erff(x * 0.7071067811865475f));
}
__device__ __forceinline__ void gload16(const void* g, void* l) {
  __builtin_amdgcn_global_load_lds(
      (const __attribute__((address_space(1))) unsigned int*)g,
      (__attribute__((address_space(3))) unsigned int*)l, 16, 0, 0);
}

// sorted-descending insert, static indexing, depth N
template <int N>
__device__ __forceinline__ void insN(float v, int j, float (&lv)[N], int (&li)[N]) {
#pragma unroll
  for (int p = N - 1; p >= 1; --p) {
    bool shiftv = v > lv[p - 1];
    bool here = (v > lv[p]) && !shiftv;
    float nv = shiftv ? lv[p - 1] : (here ? v : lv[p]);
    int ni = shiftv ? li[p - 1] : (here ? j : li[p]);
    lv[p] = nv; li[p] = ni;
  }
  if (v > lv[0]) { lv[0] = v; li[0] = j; }
}

__global__ __launch_bounds__(256) void cvt_bf16(const float* __restrict__ in,
                                                unsigned short* __restrict__ out, int n4) {
  int t = blockIdx.x * 256 + threadIdx.x;
  if (t >= n4) return;
  float4 f = ((const float4*)in)[t];
  ushort4 r;
  r.x = f2bf(f.x); r.y = f2bf(f.y); r.z = f2bf(f.z); r.w = f2bf(f.w);
  ((ushort4*)out)[t] = r;
}

// f32 [rows][K] -> bf16 hi/lo interleaved [rows][2K] (row = [hi(K) | lo(K)])
__global__ __launch_bounds__(256) void split2(const float* __restrict__ in,
                                              unsigned short* __restrict__ out,
                                              int K, int n4) {
  int t = blockIdx.x * 256 + threadIdx.x;
  if (t >= n4) return;
  int kq = K >> 2;
  int row = t / kq, c4 = t - row * kq;
  float4 f = ((const float4*)in)[t];
  ushort4 h, l;
  float x;
  x = f.x; h.x = f2bf(x); l.x = f2bf(x - bf2f(h.x));
  x = f.y; h.y = f2bf(x); l.y = f2bf(x - bf2f(h.y));
  x = f.z; h.z = f2bf(x); l.z = f2bf(x - bf2f(h.z));
  x = f.w; h.w = f2bf(x); l.w = f2bf(x - bf2f(h.w));
  *(ushort4*)(out + (size_t)row * 2 * K + c4 * 4) = h;
  *(ushort4*)(out + (size_t)row * 2 * K + K + c4 * 4) = l;
}

// W [K x N] f32 -> transposed hi/lo interleaved bf16 [N][2K]
__global__ __launch_bounds__(256) void split_wt2(const float* __restrict__ W,
                                                 unsigned short* __restrict__ t2,
                                                 int K, int N) {
  __shared__ float tile[32][33];
  int kb = blockIdx.x * 32, nb = blockIdx.y * 32;
  int tx = threadIdx.x & 31, ty = threadIdx.x >> 5;
#pragma unroll
  for (int p = 0; p < 4; ++p)
    tile[ty + p * 8][tx] = W[(size_t)(kb + ty + p * 8) * N + nb + tx];
  __syncthreads();
#pragma unroll
  for (int p = 0; p < 4; ++p) {
    int n = ty + p * 8;
    float x = tile[tx][n];
    unsigned short h = f2bf(x);
    unsigned short l = f2bf(x - bf2f(h));
    t2[(size_t)(nb + n) * (2 * K) + kb + tx] = h;
    t2[(size_t)(nb + n) * (2 * K) + K + kb + tx] = l;
  }
}

// -------- fp32 SGEMM for G only. 64x128 tile. Per-element fmaf chain order (k ascending,
// single acc) -> output independent of tiling; selection-critical, keep fp32. --------
__global__ __launch_bounds__(256) void sgemm_f32(const float* __restrict__ A,
                                                 const float* __restrict__ Bm,
                                                 float* __restrict__ C, int N, int K) {
  __shared__ float As[16][68];
  __shared__ float Bs[16][132];
  const int r0 = blockIdx.x * 64, c0 = blockIdx.y * 128;
  const int tid = threadIdx.x;
  const int tr = tid >> 4, tc = tid & 15;
  float acc[4][8];
#pragma unroll
  for (int i = 0; i < 4; ++i)
#pragma unroll
    for (int j = 0; j < 8; ++j) acc[i][j] = 0.f;

  for (int k0 = 0; k0 < K; k0 += 16) {
    {
      int row = tid >> 2, kq = tid & 3;
      float4 a4 = *(const float4*)(A + (size_t)(r0 + row) * K + k0 + kq * 4);
      As[kq * 4 + 0][row] = a4.x; As[kq * 4 + 1][row] = a4.y;
      As[kq * 4 + 2][row] = a4.z; As[kq * 4 + 3][row] = a4.w;
#pragma unroll
      for (int s = 0; s < 2; ++s) {
        int ch = tid + s * 256;
        int kk = ch >> 5, nq = ch & 31;
        *(float4*)&Bs[kk][nq * 4] = *(const float4*)(Bm + (size_t)(k0 + kk) * N + c0 + nq * 4);
      }
    }
    __syncthreads();
#pragma unroll
    for (int k = 0; k < 16; ++k) {
      float a[4], b[8];
      *(float4*)&a[0] = *(const float4*)&As[k][tr * 4];
      *(float4*)&b[0] = *(const float4*)&Bs[k][tc * 8];
      *(float4*)&b[4] = *(const float4*)&Bs[k][tc * 8 + 4];
#pragma unroll
      for (int i = 0; i < 4; ++i)
#pragma unroll
        for (int j = 0; j < 8; ++j) acc[i][j] = fmaf(a[i], b[j], acc[i][j]);
    }
    __syncthreads();
  }
#pragma unroll
  for (int i = 0; i < 4; ++i) {
    int r = r0 + tr * 4 + i;
#pragma unroll
    for (int jq = 0; jq < 2; ++jq)
      *(float4*)(C + (size_t)r * N + c0 + tc * 8 + jq * 4) = *(float4*)&acc[i][jq * 4];
  }
}

// ---------- bf16 MFMA GEMM, 128x128 tile, swizzled staging (conflict-free frag reads) ------
template <int EPI>
__global__ __launch_bounds__(256) void gemm_bt(const unsigned short* __restrict__ A,
                                               const unsigned short* __restrict__ Bt,
                                               const float* __restrict__ bias,
                                               float* __restrict__ C, int N, int K) {
  __shared__ __align__(16) unsigned short As[128 * 64];
  __shared__ __align__(16) unsigned short Bs[128 * 64];
  const int r0 = blockIdx.x * 128, c0 = blockIdx.y * 128;
  const int tid = threadIdx.x, lane = tid & 63, w = tid >> 6;
  const int wr = w >> 1, wc = w & 1;
  f32x4 acc[4][4];
  const f32x4 z4 = {0.f, 0.f, 0.f, 0.f};
#pragma unroll
  for (int i = 0; i < 4; ++i)
#pragma unroll
    for (int j = 0; j < 4; ++j) acc[i][j] = z4;

  const int srow = w * 32 + (lane >> 3);
  const int ksl = (lane & 7) ^ (lane >> 3);
  const unsigned short* aSrc = A + (size_t)(r0 + srow) * K + ksl * 8;
  const unsigned short* bSrc = Bt + (size_t)(c0 + srow) * K + ksl * 8;
  const int rsw = (lane & 7);

  for (int k0 = 0; k0 < K; k0 += 64) {
#pragma unroll
    for (int t = 0; t < 4; ++t) {
      gload16(aSrc + k0 + (size_t)t * 8 * K, (char*)As + (w * 32 + t * 8) * 128);
      gload16(bSrc + k0 + (size_t)t * 8 * K, (char*)Bs + (w * 32 + t * 8) * 128);
    }
    __syncthreads();
#pragma unroll
    for (int ks = 0; ks < 2; ++ks) {
      short8v af[4], bf[4];
      const int slot = ((ks * 4 + (lane >> 4)) ^ rsw) << 4;
#pragma unroll
      for (int f = 0; f < 4; ++f) {
        af[f] = *(const short8v*)((const char*)As + (wr * 64 + f * 16 + (lane & 15)) * 128 + slot);
        bf[f] = *(const short8v*)((const char*)Bs + (wc * 64 + f * 16 + (lane & 15)) * 128 + slot);
      }
#pragma unroll
      for (int fi = 0; fi < 4; ++fi)
#pragma unroll
        for (int fj = 0; fj < 4; ++fj)
          acc[fi][fj] = __builtin_amdgcn_mfma_f32_16x16x32_bf16(af[fi], bf[fj], acc[fi][fj], 0, 0, 0);
    }
    __syncthreads();
  }
#pragma unroll
  for (int fi = 0; fi < 4; ++fi)
#pragma unroll
    for (int fj = 0; fj < 4; ++fj) {
      int col = c0 + wc * 64 + fj * 16 + (lane & 15);
      int rowb = r0 + wr * 64 + fi * 16 + (lane >> 4) * 4;
#pragma unroll
      for (int r = 0; r < 4; ++r) {
        size_t idx = (size_t)(rowb + r) * N + col;
        float x = acc[fi][fj][r];
        if constexpr (EPI) x = gelu_f(x + bias[col]);
        C[idx] = x;
      }
    }
}

// ---------- fused S = Gh@Xh^T + per-row approx top-8-per-quarter by bf16(S) ----------
// grid (64 row-blocks, 8 col-chunks of 1024); 512 thr = 8 waves (2 wr x 4 wc), wave 64x32
__global__ __launch_bounds__(512, 4) void s_topk(const unsigned short* __restrict__ Gh,
                                                 const unsigned short* __restrict__ Xh,
                                                 float* __restrict__ pv, int* __restrict__ pix) {
  __shared__ __align__(16) unsigned short As[128 * 64];   // 16 KB
  __shared__ __align__(16) unsigned short Bs[128 * 64];   // 16 KB
  __shared__ __align__(16) unsigned short St[128 * 128];  // 32 KB
  const int r0 = blockIdx.x * 128;
  const int chunk = blockIdx.y;
  const int tid = threadIdx.x, lane = tid & 63, w = tid >> 6;
  const int wr = w >> 2, wc = w & 3;
  float lv[8]; int li[8];
#pragma unroll
  for (int q = 0; q < 8; ++q) { lv[q] = -1e30f; li[q] = 0; }

  // staging map: thread stages rows (tid>>3) and (tid>>3)+64, k-slot pre-swizzled
  const int strow = tid >> 3, sslot = tid & 7;
  const int ksl = sslot ^ (strow & 7);
  const unsigned short* aSrc = Gh + (size_t)(r0 + strow) * 768 + ksl * 8;
  char* aDst0 = (char*)As + strow * 128 + sslot * 16;
  char* bDst0 = (char*)Bs + strow * 128 + sslot * 16;
  const int rsw = (lane & 7);
  const int srow = tid & 127, sg = tid >> 7;   // scan: row, col-quarter

  for (int jt = 0; jt < 8; ++jt) {
    const int j0 = chunk * 1024 + jt * 128;
    const unsigned short* bSrc = Xh + (size_t)(j0 + strow) * 768 + ksl * 8;
    f32x4 acc[4][2];
    const f32x4 z4 = {0.f, 0.f, 0.f, 0.f};
#pragma unroll
    for (int i = 0; i < 4; ++i)
#pragma unroll
      for (int j = 0; j < 2; ++j) acc[i][j] = z4;

    for (int k0 = 0; k0 < 768; k0 += 64) {
      gload16(aSrc + k0, aDst0);
      gload16(aSrc + k0 + (size_t)64 * 768, aDst0 + 64 * 128);
      gload16(bSrc + k0, bDst0);
      gload16(bSrc + k0 + (size_t)64 * 768, bDst0 + 64 * 128);
      __syncthreads();
#pragma unroll
      for (int ks = 0; ks < 2; ++ks) {
        short8v af[4], bf[2];
        const int slot = ((ks * 4 + (lane >> 4)) ^ rsw) << 4;
#pragma unroll
        for (int f = 0; f < 4; ++f)
          af[f] = *(const short8v*)((const char*)As + (wr * 64 + f * 16 + (lane & 15)) * 128 + slot);
#pragma unroll
        for (int f = 0; f < 2; ++f)
          bf[f] = *(const short8v*)((const char*)Bs + (wc * 32 + f * 16 + (lane & 15)) * 128 + slot);
#pragma unroll
        for (int fi = 0; fi < 4; ++fi)
#pragma unroll
          for (int fj = 0; fj < 2; ++fj)
            acc[fi][fj] = __builtin_amdgcn_mfma_f32_16x16x32_bf16(af[fi], bf[fj], acc[fi][fj], 0, 0, 0);
      }
      __syncthreads();
    }
    // single-phase epilogue: all 8 waves write their 64x32 region of swizzled St (acc dies here)
#pragma unroll
    for (int fi = 0; fi < 4; ++fi)
#pragma unroll
      for (int fj = 0; fj < 2; ++fj) {
        int col = wc * 32 + fj * 16 + (lane & 15);
#pragma unroll
        for (int r = 0; r < 4; ++r) {
          int row = wr * 64 + fi * 16 + (lane >> 4) * 4 + r;
          int byo = (row * 256 + col * 2) ^ ((row & 7) << 4);
          *(unsigned short*)((char*)St + byo) = f2bf(acc[fi][fj][r]);
        }
      }
    __syncthreads();
    // scan: thread owns (row srow, 32-col quarter sg)
#pragma unroll
    for (int cb = 0; cb < 4; ++cb) {
      int byo = (srow * 256 + sg * 64 + cb * 16) ^ ((srow & 7) << 4);
      short8v v8 = *(const short8v*)((const char*)St + byo);
#pragma unroll
      for (int e = 0; e < 8; ++e) {
        float v = bf2f((unsigned short)v8[e]);
        if (v > lv[7]) insN<8>(v, j0 + sg * 32 + cb * 8 + e, lv, li);
      }
    }
    __syncthreads();   // scan done before next jt's epilogue overwrites St
  }
  // write per-(row, chunk, quarter) top-8 straight to global; merge16 handles the rest
  size_t basep = (((size_t)(r0 + srow) * 8 + chunk) * 4 + sg) * 8;
#pragma unroll
  for (int q = 0; q < 8; ++q) { pv[basep + q] = lv[q]; pix[basep + q] = li[q]; }
}

// merge 8 chunks x 4 quarters x 8 = 256 partial entries per row -> global top-16 candidates
__global__ __launch_bounds__(256) void merge16(const float* __restrict__ pv,
                                               const int* __restrict__ pix,
                                               int* __restrict__ gidx) {
  int row = blockIdx.x * 256 + threadIdx.x;
  float lv[16]; int li[16];
#pragma unroll
  for (int q = 0; q < 16; ++q) { lv[q] = -1e30f; li[q] = 0; }
  for (int ch = 0; ch < 8; ++ch)
#pragma unroll
    for (int g = 0; g < 4; ++g) {
      size_t base = (((size_t)row * 8 + ch) * 4 + g) * 8;
#pragma unroll
      for (int q = 0; q < 8; ++q) {
        float v = pv[base + q];
        if (v > lv[15]) insN<16>(v, pix[base + q], lv, li);
      }
    }
#pragma unroll
  for (int q = 0; q < 16; ++q) gidx[row * 16 + q] = li[q];
}

// exact f32 re-evaluation of 16 candidates (incl. Ae blend), exact top-5 (ties -> lower index)
__global__ __launch_bounds__(256) void refine5(const float* __restrict__ G,
                                               const float* __restrict__ X,
                                               const float* __restrict__ Ae,
                                               const int* __restrict__ gidx,
                                               const float* __restrict__ ralpha,
                                               int* __restrict__ t5i, float* __restrict__ t5v) {
  int i = blockIdx.x * 4 + (threadIdx.x >> 6);
  int lane = threadIdx.x & 63;
  int c = lane >> 2, s = lane & 3;
  float sa = 1.f / (1.f + expf(-ralpha[0]));
  int j = gidx[i * 16 + c];
  const float* g = G + (size_t)i * 768;
  const float* x = X + (size_t)j * 768;
  float a = 0.f;
#pragma unroll 8
  for (int t = 0; t < 192; ++t) a = fmaf(g[s + 4 * t], x[s + 4 * t], a);
  a += __shfl_xor(a, 1);
  a += __shfl_xor(a, 2);
  float v = sa * Ae[(size_t)i * 8192 + j] + (1.f - sa) * fmaxf(a, 0.f);
  float vs[16]; int js[16];
#pragma unroll
  for (int q = 0; q < 16; ++q) { vs[q] = __shfl(v, q * 4); js[q] = __shfl(j, q * 4); }
  if (lane == 0) {
    unsigned used = 0;
#pragma unroll
    for (int t = 0; t < 5; ++t) {
      float bv = -1e30f; int bj = 0; int bq = 0; bool any = false;
#pragma unroll
      for (int q = 0; q < 16; ++q) {
        bool ok = ((used >> q) & 1u) == 0u;
        bool better = ok && (!any || vs[q] > bv || (vs[q] == bv && js[q] < bj));
        bv = better ? vs[q] : bv; bj = better ? js[q] : bj; bq = better ? q : bq;
        any = any || better;
      }
      used |= (1u << bq);
      t5v[(size_t)i * 5 + t] = bv;
      t5i[(size_t)i * 5 + t] = bj;
    }
  }
}

// -------- symmetrized sparse-A construction (canonical-pair dedup) --------
__global__ void edge_deg(const int* __restrict__ t5i, int* __restrict__ deg) {
  int e = blockIdx.x * 256 + threadIdx.x;
  if (e >= 40960) return;
  int i = e / 5, t = e - i * 5;
  int j = t5i[i * 5 + t];
  if (j == i) return;
  bool rev = false;
#pragma unroll
  for (int u = 0; u < 5; ++u) rev = rev || (t5i[j * 5 + u] == i);
  if (!rev || i < j) { atomicAdd(&deg[i], 1); atomicAdd(&deg[j], 1); }
}

__global__ void scan8k(const int* __restrict__ deg, int* __restrict__ off) {
  __shared__ int sums[256];
  int tid = threadIdx.x;
  int base = tid * 32;
  int s = 0;
  for (int u = 0; u < 32; ++u) s += deg[base + u];
  sums[tid] = s;
  __syncthreads();
  for (int d = 1; d < 256; d <<= 1) {
    int v = (tid >= d) ? sums[tid - d] : 0;
    __syncthreads();
    sums[tid] += v;
    __syncthreads();
  }
  int run = tid ? sums[tid - 1] : 0;
  for (int u = 0; u < 32; ++u) { off[base + u] = run; run += deg[base + u]; }
  if (tid == 255) off[8192] = run;
}

__global__ __launch_bounds__(256) void edge_fill(const int* __restrict__ t5i,
                                                 const float* __restrict__ t5v,
                                                 const float* __restrict__ G,
                                                 const float* __restrict__ X,
                                                 const float* __restrict__ Ae,
                                                 const float* __restrict__ ralpha,
                                                 const int* __restrict__ off,
                                                 int* __restrict__ cursor,
                                                 int* __restrict__ ccol, float* __restrict__ cval) {
  int e = blockIdx.x * 4 + (threadIdx.x >> 6);
  if (e >= 40960) return;
  int lane = threadIdx.x & 63;
  int i = e / 5, t = e - i * 5;
  int j = t5i[i * 5 + t];
  if (j == i) return;
  int rev = -1;
#pragma unroll
  for (int u = 0; u < 5; ++u)
    if (t5i[j * 5 + u] == i) rev = u;
  if (!(rev < 0 || i < j)) return;
  float vji;
  if (rev >= 0) {
    vji = t5v[j * 5 + rev];
  } else {
    const float* g = G + (size_t)j * 768;
    const float* x = X + (size_t)i * 768;
    float a = 0.f;
#pragma unroll
    for (int u = 0; u < 12; ++u) a = fmaf(g[lane + 64 * u], x[lane + 64 * u], a);
#pragma unroll
    for (int d = 32; d; d >>= 1) a += __shfl_xor(a, d);
    float sa = 1.f / (1.f + expf(-ralpha[0]));
    vji = sa * Ae[(size_t)j * 8192 + i] + (1.f - sa) * fmaxf(a, 0.f);
  }
  if (lane == 0) {
    float vij = t5v[i * 5 + t];
    int p0 = off[i] + atomicAdd(&cursor[i], 1);
    ccol[p0] = j; cval[p0] = vij;
    int p1 = off[j] + atomicAdd(&cursor[j], 1);
    ccol[p1] = i; cval[p1] = vji;
  }
}

// M = D^-1 * (X[i] + sum val * X[j]) ; one block per row
__global__ __launch_bounds__(256) void gather_gcn(const float* __restrict__ X,
                                                  const int* __restrict__ off,
                                                  const int* __restrict__ ccol,
                                                  const float* __restrict__ cval,
                                                  float* __restrict__ M) {
  __shared__ float red[256];
  __shared__ float sdinv;
  int i = blockIdx.x, tid = threadIdx.x;
  int s0 = off[i], cnt = off[i + 1] - s0;
  float s = 0.f;
  for (int e = tid; e < cnt; e += 256) s += cval[s0 + e];
  red[tid] = s;
  __syncthreads();
  for (int d = 128; d; d >>= 1) {
    if (tid < d) red[tid] += red[tid + d];
    __syncthreads();
  }
  if (tid == 0) sdinv = 1.f / fmaxf(1.f + red[0], 1e-8f);
  __syncthreads();
  float dinv = sdinv;
  const float* xi = X + (size_t)i * 768;
  float a0 = xi[tid], a1 = xi[tid + 256], a2 = xi[tid + 512];
  for (int e = 0; e < cnt; ++e) {
    float v = cval[s0 + e];
    const float* xr = X + (size_t)ccol[s0 + e] * 768;
    a0 = fmaf(v, xr[tid], a0);
    a1 = fmaf(v, xr[tid + 256], a1);
    a2 = fmaf(v, xr[tid + 512], a2);
  }
  float* mi = M + (size_t)i * 768;
  mi[tid] = a0 * dinv; mi[tid + 256] = a1 * dinv; mi[tid + 512] = a2 * dinv;
}

__global__ __launch_bounds__(256) void final_head(const float* __restrict__ h2,
                                                  const float* __restrict__ W3,
                                                  const float* __restrict__ b3,
                                                  float* __restrict__ out) {
  int i = blockIdx.x * 4 + (threadIdx.x >> 6);
  int lane = threadIdx.x & 63;
  const float* r = h2 + (size_t)i * 256;
  float s = r[lane] * W3[lane] + r[lane + 64] * W3[lane + 64] +
            r[lane + 128] * W3[lane + 128] + r[lane + 192] * W3[lane + 192];
#pragma unroll
  for (int d = 32; d; d >>= 1) s += __shfl_xor(s, d);
  if (lane == 0) out[i] = s + b3[0];
}

extern "C" void kernel_launch(void* const* d_in, const int* in_sizes, int n_in,
                              void* d_out, int out_size, void* d_ws, size_t ws_size,
                              hipStream_t stream) {
  const float* X   = (const float*)d_in[0];
  const float* Ae  = (const float*)d_in[1];
  const float* Wg  = (const float*)d_in[2];
  const float* ra  = (const float*)d_in[3];
  const float* Wgc = (const float*)d_in[4];
  const float* bgc = (const float*)d_in[5];
  const float* W1  = (const float*)d_in[6];
  const float* b1  = (const float*)d_in[7];
  const float* W2  = (const float*)d_in[8];
  const float* b2  = (const float*)d_in[9];
  const float* W3  = (const float*)d_in[10];
  const float* b3  = (const float*)d_in[11];
  float* out = (float*)d_out;

  char* w = (char*)d_ws;
  size_t off_ = 0;
  auto take = [&](size_t n) -> void* {
    void* p = w + off_;
    off_ += (n + 255) & ~(size_t)255;
    return p;
  };
  float* G            = (float*)take((size_t)8192 * 768 * 4);          // 25.17 MB
  unsigned short* Xh  = (unsigned short*)take((size_t)8192 * 768 * 2); // 12.58
  unsigned short* Gh  = (unsigned short*)take((size_t)8192 * 768 * 2); // 12.58
  float* pv           = (float*)take((size_t)8192 * 256 * 4);          // 8.39
  int* pix            = (int*)take((size_t)8192 * 256 * 4);            // 8.39
  int* gidx           = (int*)take((size_t)8192 * 16 * 4);
  int* t5i            = (int*)take((size_t)8192 * 5 * 4);
  float* t5v          = (float*)take((size_t)8192 * 5 * 4);
  int* deg            = (int*)take((size_t)8192 * 4);
  int* offr           = (int*)take((size_t)8193 * 4);
  int* cur            = (int*)take((size_t)8192 * 4);
  int* ccol           = (int*)take((size_t)81920 * 4);
  float* cval         = (float*)take((size_t)81920 * 4);
  unsigned short* Wc2 = (unsigned short*)take((size_t)768 * 1536 * 2); // 2.36
  unsigned short* W12 = (unsigned short*)take((size_t)512 * 1536 * 2); // 1.57
  unsigned short* W22 = (unsigned short*)take((size_t)256 * 1024 * 2); // 0.52
  // total ~72 MB (< R1's proven 85.5 MB)

  // region reuse (stream-ordered):
  float* Mf  = (float*)Xh;   // Xh+Gh (25.17 MB, dead after s_topk): Mf -> Hf -> h1f
  float* Hf  = (float*)Xh;
  float* h1f = (float*)Xh;
  unsigned short* A2 = (unsigned short*)G;   // G (dead after edge_fill): activation planes
  float* h2f = (float*)pv;   // pv+pix (16.8 MB, dead after merge16): h2 (8.39 MB)

  // 1. G = X @ Wg — fp32, k-ascending chain (selection-critical)
  sgemm_f32<<<dim3(128, 6), 256, 0, stream>>>(X, Wg, G, 768, 768);
  // 2. bf16 copies for candidate pass
  cvt_bf16<<<6144, 256, 0, stream>>>(X, Xh, 1572864);
  cvt_bf16<<<6144, 256, 0, stream>>>(G, Gh, 1572864);
  // 3. interleaved weight planes for MLP
  split_wt2<<<dim3(24, 24), 256, 0, stream>>>(Wgc, Wc2, 768, 768);
  split_wt2<<<dim3(24, 16), 256, 0, stream>>>(W1, W12, 768, 512);
  split_wt2<<<dim3(16, 8), 256, 0, stream>>>(W2, W22, 512, 256);

  // 4. fused S + per-row/quarter top-8 candidates (exact blend in refine5)
  s_topk<<<dim3(64, 8), 512, 0, stream>>>(Gh, Xh, pv, pix);
  merge16<<<32, 256, 0, stream>>>(pv, pix, gidx);
  refine5<<<2048, 256, 0, stream>>>(G, X, Ae, gidx, ra, t5i, t5v);

  // 5. sparse symmetric A as CSR
  hipMemsetAsync(deg, 0, 8192 * 4, stream);
  hipMemsetAsync(cur, 0, 8192 * 4, stream);
  edge_deg<<<160, 256, 0, stream>>>(t5i, deg);
  scan8k<<<1, 256, 0, stream>>>(deg, offr);
  edge_fill<<<10240, 256, 0, stream>>>(t5i, t5v, G, X, Ae, ra, offr, cur, ccol, cval);

  // 6. M = A_norm @ X
  gather_gcn<<<8192, 256, 0, stream>>>(X, offr, ccol, cval, Mf);

  // 7. H = gelu(M @ Wgcn + bgc) — one split-bf16 pass, K=1536
  split2<<<6144, 256, 0, stream>>>(Mf, A2, 768, 1572864);
  gemm_bt<1><<<dim3(64, 6), 256, 0, stream>>>(A2, Wc2, bgc, Hf, 768, 1536);

  // 8. h1 = gelu(H @ W1 + b1)
  split2<<<6144, 256, 0, stream>>>(Hf, A2, 768, 1572864);
  gemm_bt<1><<<dim3(64, 4), 256, 0, stream>>>(A2, W12, b1, h1f, 512, 1536);

  // 9. h2 = gelu(h1 @ W2 + b2)
  split2<<<4096, 256, 0, stream>>>(h1f, A2, 512, 1048576);
  gemm_bt<1><<<dim3(64, 2), 256, 0, stream>>>(A2, W22, b2, h2f, 256, 1024);

  // 10. out = h2 @ W3 + b3
  final_head<<<2048, 256, 0, stream>>>(h2f, W3, b3, out);

  (void)in_sizes; (void)n_in; (void)out_size; (void)ws_size;
}

// Round 6
// 717.773 us; speedup vs baseline: 1.4436x; 1.0054x over previous
//
#include <hip/hip_runtime.h>
#include <math.h>

// SimpleGSLModel: B=8192, D=768, TOP_K=5
// R6: s_topk v3 — swapped MFMA operands (S^T tiles: col=i, row=j) make the top-k reduction
//     lane-local: in-register top-5 per (lane, i), NO St LDS round-trip, no epilogue barriers.
//     1-D grid, chunk = bid&7 -> each chunk's Xh slice pinned to one XCD's L2.
//     bf16(G) fused into sgemm epilogue (G f32 path bitwise unchanged).
//     merge16 merges 8 chunks x 8 lane-slots x 5. Everything else R5-verbatim (passed).

typedef __attribute__((ext_vector_type(8))) short short8v;
typedef __attribute__((ext_vector_type(4))) float f32x4;

__device__ __forceinline__ unsigned short f2bf(float f) {
  unsigned u = __float_as_uint(f);
  u += 0x7fffu + ((u >> 16) & 1u);   // RNE
  return (unsigned short)(u >> 16);
}
__device__ __forceinline__ float bf2f(unsigned short h) {
  return __uint_as_float(((unsigned)h) << 16);
}
__device__ __forceinline__ float gelu_f(float x) {
  return 0.5f * x * (1.f + erff(x * 0.7071067811865475f));
}
__device__ __forceinline__ void gload16(const void* g, void* l) {
  __builtin_amdgcn_global_load_lds(
      (const __attribute__((address_space(1))) unsigned int*)g,
      (__attribute__((address_space(3))) unsigned int*)l, 16, 0, 0);
}

// sorted-descending insert, static indexing, depth N
template <int N>
__device__ __forceinline__ void insN(float v, int j, float (&lv)[N], int (&li)[N]) {
#pragma unroll
  for (int p = N - 1; p >= 1; --p) {
    bool shiftv = v > lv[p - 1];
    bool here = (v > lv[p]) && !shiftv;
    float nv = shiftv ? lv[p - 1] : (here ? v : lv[p]);
    int ni = shiftv ? li[p - 1] : (here ? j : li[p]);
    lv[p] = nv; li[p] = ni;
  }
  if (v > lv[0]) { lv[0] = v; li[0] = j; }
}

__global__ __launch_bounds__(256) void cvt_bf16(const float* __restrict__ in,
                                                unsigned short* __restrict__ out, int n4) {
  int t = blockIdx.x * 256 + threadIdx.x;
  if (t >= n4) return;
  float4 f = ((const float4*)in)[t];
  ushort4 r;
  r.x = f2bf(f.x); r.y = f2bf(f.y); r.z = f2bf(f.z); r.w = f2bf(f.w);
  ((ushort4*)out)[t] = r;
}

// f32 [rows][K] -> bf16 hi/lo interleaved [rows][2K] (row = [hi(K) | lo(K)])
__global__ __launch_bounds__(256) void split2(const float* __restrict__ in,
                                              unsigned short* __restrict__ out,
                                              int K, int n4) {
  int t = blockIdx.x * 256 + threadIdx.x;
  if (t >= n4) return;
  int kq = K >> 2;
  int row = t / kq, c4 = t - row * kq;
  float4 f = ((const float4*)in)[t];
  ushort4 h, l;
  float x;
  x = f.x; h.x = f2bf(x); l.x = f2bf(x - bf2f(h.x));
  x = f.y; h.y = f2bf(x); l.y = f2bf(x - bf2f(h.y));
  x = f.z; h.z = f2bf(x); l.z = f2bf(x - bf2f(h.z));
  x = f.w; h.w = f2bf(x); l.w = f2bf(x - bf2f(h.w));
  *(ushort4*)(out + (size_t)row * 2 * K + c4 * 4) = h;
  *(ushort4*)(out + (size_t)row * 2 * K + K + c4 * 4) = l;
}

// W [K x N] f32 -> transposed hi/lo interleaved bf16 [N][2K]
__global__ __launch_bounds__(256) void split_wt2(const float* __restrict__ W,
                                                 unsigned short* __restrict__ t2,
                                                 int K, int N) {
  __shared__ float tile[32][33];
  int kb = blockIdx.x * 32, nb = blockIdx.y * 32;
  int tx = threadIdx.x & 31, ty = threadIdx.x >> 5;
#pragma unroll
  for (int p = 0; p < 4; ++p)
    tile[ty + p * 8][tx] = W[(size_t)(kb + ty + p * 8) * N + nb + tx];
  __syncthreads();
#pragma unroll
  for (int p = 0; p < 4; ++p) {
    int n = ty + p * 8;
    float x = tile[tx][n];
    unsigned short h = f2bf(x);
    unsigned short l = f2bf(x - bf2f(h));
    t2[(size_t)(nb + n) * (2 * K) + kb + tx] = h;
    t2[(size_t)(nb + n) * (2 * K) + K + kb + tx] = l;
  }
}

// -------- fp32 SGEMM for G. 64x128 tile; per-element fmaf chain (k ascending, single acc)
// -> bitwise-stable output (selection-critical). Fused bf16 copy of the result. --------
__global__ __launch_bounds__(256) void sgemm_f32(const float* __restrict__ A,
                                                 const float* __restrict__ Bm,
                                                 float* __restrict__ C,
                                                 unsigned short* __restrict__ Cbf,
                                                 int N, int K) {
  __shared__ float As[16][68];
  __shared__ float Bs[16][132];
  const int r0 = blockIdx.x * 64, c0 = blockIdx.y * 128;
  const int tid = threadIdx.x;
  const int tr = tid >> 4, tc = tid & 15;
  float acc[4][8];
#pragma unroll
  for (int i = 0; i < 4; ++i)
#pragma unroll
    for (int j = 0; j < 8; ++j) acc[i][j] = 0.f;

  for (int k0 = 0; k0 < K; k0 += 16) {
    {
      int row = tid >> 2, kq = tid & 3;
      float4 a4 = *(const float4*)(A + (size_t)(r0 + row) * K + k0 + kq * 4);
      As[kq * 4 + 0][row] = a4.x; As[kq * 4 + 1][row] = a4.y;
      As[kq * 4 + 2][row] = a4.z; As[kq * 4 + 3][row] = a4.w;
#pragma unroll
      for (int s = 0; s < 2; ++s) {
        int ch = tid + s * 256;
        int kk = ch >> 5, nq = ch & 31;
        *(float4*)&Bs[kk][nq * 4] = *(const float4*)(Bm + (size_t)(k0 + kk) * N + c0 + nq * 4);
      }
    }
    __syncthreads();
#pragma unroll
    for (int k = 0; k < 16; ++k) {
      float a[4], b[8];
      *(float4*)&a[0] = *(const float4*)&As[k][tr * 4];
      *(float4*)&b[0] = *(const float4*)&Bs[k][tc * 8];
      *(float4*)&b[4] = *(const float4*)&Bs[k][tc * 8 + 4];
#pragma unroll
      for (int i = 0; i < 4; ++i)
#pragma unroll
        for (int j = 0; j < 8; ++j) acc[i][j] = fmaf(a[i], b[j], acc[i][j]);
    }
    __syncthreads();
  }
#pragma unroll
  for (int i = 0; i < 4; ++i) {
    int r = r0 + tr * 4 + i;
#pragma unroll
    for (int jq = 0; jq < 2; ++jq) {
      *(float4*)(C + (size_t)r * N + c0 + tc * 8 + jq * 4) = *(float4*)&acc[i][jq * 4];
      ushort4 hb;
      hb.x = f2bf(acc[i][jq * 4 + 0]); hb.y = f2bf(acc[i][jq * 4 + 1]);
      hb.z = f2bf(acc[i][jq * 4 + 2]); hb.w = f2bf(acc[i][jq * 4 + 3]);
      *(ushort4*)(Cbf + (size_t)r * N + c0 + tc * 8 + jq * 4) = hb;
    }
  }
}

// ---------- bf16 MFMA GEMM, 128x128 tile, swizzled staging (conflict-free frag reads) ------
template <int EPI>
__global__ __launch_bounds__(256) void gemm_bt(const unsigned short* __restrict__ A,
                                               const unsigned short* __restrict__ Bt,
                                               const float* __restrict__ bias,
                                               float* __restrict__ C, int N, int K) {
  __shared__ __align__(16) unsigned short As[128 * 64];
  __shared__ __align__(16) unsigned short Bs[128 * 64];
  const int r0 = blockIdx.x * 128, c0 = blockIdx.y * 128;
  const int tid = threadIdx.x, lane = tid & 63, w = tid >> 6;
  const int wr = w >> 1, wc = w & 1;
  f32x4 acc[4][4];
  const f32x4 z4 = {0.f, 0.f, 0.f, 0.f};
#pragma unroll
  for (int i = 0; i < 4; ++i)
#pragma unroll
    for (int j = 0; j < 4; ++j) acc[i][j] = z4;

  const int srow = w * 32 + (lane >> 3);
  const int ksl = (lane & 7) ^ (lane >> 3);
  const unsigned short* aSrc = A + (size_t)(r0 + srow) * K + ksl * 8;
  const unsigned short* bSrc = Bt + (size_t)(c0 + srow) * K + ksl * 8;
  const int rsw = (lane & 7);

  for (int k0 = 0; k0 < K; k0 += 64) {
#pragma unroll
    for (int t = 0; t < 4; ++t) {
      gload16(aSrc + k0 + (size_t)t * 8 * K, (char*)As + (w * 32 + t * 8) * 128);
      gload16(bSrc + k0 + (size_t)t * 8 * K, (char*)Bs + (w * 32 + t * 8) * 128);
    }
    __syncthreads();
#pragma unroll
    for (int ks = 0; ks < 2; ++ks) {
      short8v af[4], bf[4];
      const int slot = ((ks * 4 + (lane >> 4)) ^ rsw) << 4;
#pragma unroll
      for (int f = 0; f < 4; ++f) {
        af[f] = *(const short8v*)((const char*)As + (wr * 64 + f * 16 + (lane & 15)) * 128 + slot);
        bf[f] = *(const short8v*)((const char*)Bs + (wc * 64 + f * 16 + (lane & 15)) * 128 + slot);
      }
#pragma unroll
      for (int fi = 0; fi < 4; ++fi)
#pragma unroll
        for (int fj = 0; fj < 4; ++fj)
          acc[fi][fj] = __builtin_amdgcn_mfma_f32_16x16x32_bf16(af[fi], bf[fj], acc[fi][fj], 0, 0, 0);
    }
    __syncthreads();
  }
#pragma unroll
  for (int fi = 0; fi < 4; ++fi)
#pragma unroll
    for (int fj = 0; fj < 4; ++fj) {
      int col = c0 + wc * 64 + fj * 16 + (lane & 15);
      int rowb = r0 + wr * 64 + fi * 16 + (lane >> 4) * 4;
#pragma unroll
      for (int r = 0; r < 4; ++r) {
        size_t idx = (size_t)(rowb + r) * N + col;
        float x = acc[fi][fj][r];
        if constexpr (EPI) x = gelu_f(x + bias[col]);
        C[idx] = x;
      }
    }
}

// ---------- fused S^T tiles + lane-local top-5 (swapped operands: col=i, row=j) ----------
// grid 512 blocks: ib = bid>>3 (i-block of 128), chunk = bid&7 (1024 j's, XCD-pinned)
// 512 thr = 8 waves (wr: j-half of 64, wc: i-quarter of 32); acc[4][2]: fi=j-frag, fj=i-frag
__global__ __launch_bounds__(512, 4) void s_topk(const unsigned short* __restrict__ Gh,
                                                 const unsigned short* __restrict__ Xh,
                                                 float* __restrict__ pv, int* __restrict__ pix) {
  __shared__ __align__(16) unsigned short As[128 * 64];   // j-tile (Xh rows) 16 KB
  __shared__ __align__(16) unsigned short Bs[128 * 64];   // i-tile (Gh rows) 16 KB
  const int bid = blockIdx.x;
  const int r0 = (bid >> 3) * 128;
  const int chunk = bid & 7;
  const int tid = threadIdx.x, lane = tid & 63, w = tid >> 6;
  const int wr = w >> 2, wc = w & 3;
  float lv0[5], lv1[5]; int li0[5], li1[5];
#pragma unroll
  for (int q = 0; q < 5; ++q) {
    lv0[q] = -1e30f; li0[q] = 0; lv1[q] = -1e30f; li1[q] = 0;
  }

  const int strow = tid >> 3, sslot = tid & 7;
  const int ksl = sslot ^ (strow & 7);
  const unsigned short* bSrc = Gh + (size_t)(r0 + strow) * 768 + ksl * 8;  // i rows, fixed
  char* aDst0 = (char*)As + strow * 128 + sslot * 16;
  char* bDst0 = (char*)Bs + strow * 128 + sslot * 16;
  const int rsw = lane & 7;

  for (int jt = 0; jt < 8; ++jt) {
    const int j0 = chunk * 1024 + jt * 128;
    const unsigned short* aSrc = Xh + (size_t)(j0 + strow) * 768 + ksl * 8;  // j rows
    f32x4 acc[4][2];
    const f32x4 z4 = {0.f, 0.f, 0.f, 0.f};
#pragma unroll
    for (int i = 0; i < 4; ++i) {
      acc[i][0] = z4; acc[i][1] = z4;
    }

    for (int k0 = 0; k0 < 768; k0 += 64) {
      gload16(aSrc + k0, aDst0);
      gload16(aSrc + k0 + (size_t)64 * 768, aDst0 + 64 * 128);
      gload16(bSrc + k0, bDst0);
      gload16(bSrc + k0 + (size_t)64 * 768, bDst0 + 64 * 128);
      __syncthreads();
#pragma unroll
      for (int ks = 0; ks < 2; ++ks) {
        short8v aj[4], bi[2];
        const int slot = ((ks * 4 + (lane >> 4)) ^ rsw) << 4;
#pragma unroll
        for (int f = 0; f < 4; ++f)
          aj[f] = *(const short8v*)((const char*)As + (wr * 64 + f * 16 + (lane & 15)) * 128 + slot);
#pragma unroll
        for (int f = 0; f < 2; ++f)
          bi[f] = *(const short8v*)((const char*)Bs + (wc * 32 + f * 16 + (lane & 15)) * 128 + slot);
#pragma unroll
        for (int fi = 0; fi < 4; ++fi) {
          acc[fi][0] = __builtin_amdgcn_mfma_f32_16x16x32_bf16(aj[fi], bi[0], acc[fi][0], 0, 0, 0);
          acc[fi][1] = __builtin_amdgcn_mfma_f32_16x16x32_bf16(aj[fi], bi[1], acc[fi][1], 0, 0, 0);
        }
      }
      __syncthreads();
    }
    // in-register scan: lane holds 16 j-values for each of 2 i's (acc dies here, no LDS)
    const int jb = j0 + wr * 64 + (lane >> 4) * 4;
#pragma unroll
    for (int fi = 0; fi < 4; ++fi)
#pragma unroll
      for (int r = 0; r < 4; ++r) {
        int jj = jb + fi * 16 + r;
        float v0 = acc[fi][0][r];
        if (v0 > lv0[4]) insN<5>(v0, jj, lv0, li0);
        float v1 = acc[fi][1][r];
        if (v1 > lv1[4]) insN<5>(v1, jj, lv1, li1);
      }
  }
  // write per-(i, chunk, slot) top-5; slot = wr*4 + lane-group
  const int slotw = wr * 4 + (lane >> 4);
  const int ib0 = r0 + wc * 32 + (lane & 15);
  size_t base0 = (((size_t)ib0 * 8 + chunk) * 8 + slotw) * 5;
#pragma unroll
  for (int q = 0; q < 5; ++q) { pv[base0 + q] = lv0[q]; pix[base0 + q] = li0[q]; }
  size_t base1 = (((size_t)(ib0 + 16) * 8 + chunk) * 8 + slotw) * 5;
#pragma unroll
  for (int q = 0; q < 5; ++q) { pv[base1 + q] = lv1[q]; pix[base1 + q] = li1[q]; }
}

// merge 8 chunks x 8 slots x 5 = 320 partial entries per row -> global top-16 candidates
__global__ __launch_bounds__(256) void merge16(const float* __restrict__ pv,
                                               const int* __restrict__ pix,
                                               int* __restrict__ gidx) {
  int row = blockIdx.x * 256 + threadIdx.x;
  float lv[16]; int li[16];
#pragma unroll
  for (int q = 0; q < 16; ++q) { lv[q] = -1e30f; li[q] = 0; }
  for (int ch = 0; ch < 8; ++ch)
#pragma unroll
    for (int sl = 0; sl < 8; ++sl) {
      size_t base = (((size_t)row * 8 + ch) * 8 + sl) * 5;
#pragma unroll
      for (int q = 0; q < 5; ++q) {
        float v = pv[base + q];
        if (v > lv[15]) insN<16>(v, pix[base + q], lv, li);
      }
    }
#pragma unroll
  for (int q = 0; q < 16; ++q) gidx[row * 16 + q] = li[q];
}

// exact f32 re-evaluation of 16 candidates (incl. Ae blend), exact top-5 (ties -> lower index)
__global__ __launch_bounds__(256) void refine5(const float* __restrict__ G,
                                               const float* __restrict__ X,
                                               const float* __restrict__ Ae,
                                               const int* __restrict__ gidx,
                                               const float* __restrict__ ralpha,
                                               int* __restrict__ t5i, float* __restrict__ t5v) {
  int i = blockIdx.x * 4 + (threadIdx.x >> 6);
  int lane = threadIdx.x & 63;
  int c = lane >> 2, s = lane & 3;
  float sa = 1.f / (1.f + expf(-ralpha[0]));
  int j = gidx[i * 16 + c];
  const float* g = G + (size_t)i * 768;
  const float* x = X + (size_t)j * 768;
  float a = 0.f;
#pragma unroll 8
  for (int t = 0; t < 192; ++t) a = fmaf(g[s + 4 * t], x[s + 4 * t], a);
  a += __shfl_xor(a, 1);
  a += __shfl_xor(a, 2);
  float v = sa * Ae[(size_t)i * 8192 + j] + (1.f - sa) * fmaxf(a, 0.f);
  float vs[16]; int js[16];
#pragma unroll
  for (int q = 0; q < 16; ++q) { vs[q] = __shfl(v, q * 4); js[q] = __shfl(j, q * 4); }
  if (lane == 0) {
    unsigned used = 0;
#pragma unroll
    for (int t = 0; t < 5; ++t) {
      float bv = -1e30f; int bj = 0; int bq = 0; bool any = false;
#pragma unroll
      for (int q = 0; q < 16; ++q) {
        bool ok = ((used >> q) & 1u) == 0u;
        bool better = ok && (!any || vs[q] > bv || (vs[q] == bv && js[q] < bj));
        bv = better ? vs[q] : bv; bj = better ? js[q] : bj; bq = better ? q : bq;
        any = any || better;
      }
      used |= (1u << bq);
      t5v[(size_t)i * 5 + t] = bv;
      t5i[(size_t)i * 5 + t] = bj;
    }
  }
}

// -------- symmetrized sparse-A construction (canonical-pair dedup) --------
__global__ void edge_deg(const int* __restrict__ t5i, int* __restrict__ deg) {
  int e = blockIdx.x * 256 + threadIdx.x;
  if (e >= 40960) return;
  int i = e / 5, t = e - i * 5;
  int j = t5i[i * 5 + t];
  if (j == i) return;
  bool rev = false;
#pragma unroll
  for (int u = 0; u < 5; ++u) rev = rev || (t5i[j * 5 + u] == i);
  if (!rev || i < j) { atomicAdd(&deg[i], 1); atomicAdd(&deg[j], 1); }
}

__global__ void scan8k(const int* __restrict__ deg, int* __restrict__ off) {
  __shared__ int sums[256];
  int tid = threadIdx.x;
  int base = tid * 32;
  int s = 0;
  for (int u = 0; u < 32; ++u) s += deg[base + u];
  sums[tid] = s;
  __syncthreads();
  for (int d = 1; d < 256; d <<= 1) {
    int v = (tid >= d) ? sums[tid - d] : 0;
    __syncthreads();
    sums[tid] += v;
    __syncthreads();
  }
  int run = tid ? sums[tid - 1] : 0;
  for (int u = 0; u < 32; ++u) { off[base + u] = run; run += deg[base + u]; }
  if (tid == 255) off[8192] = run;
}

__global__ __launch_bounds__(256) void edge_fill(const int* __restrict__ t5i,
                                                 const float* __restrict__ t5v,
                                                 const float* __restrict__ G,
                                                 const float* __restrict__ X,
                                                 const float* __restrict__ Ae,
                                                 const float* __restrict__ ralpha,
                                                 const int* __restrict__ off,
                                                 int* __restrict__ cursor,
                                                 int* __restrict__ ccol, float* __restrict__ cval) {
  int e = blockIdx.x * 4 + (threadIdx.x >> 6);
  if (e >= 40960) return;
  int lane = threadIdx.x & 63;
  int i = e / 5, t = e - i * 5;
  int j = t5i[i * 5 + t];
  if (j == i) return;
  int rev = -1;
#pragma unroll
  for (int u = 0; u < 5; ++u)
    if (t5i[j * 5 + u] == i) rev = u;
  if (!(rev < 0 || i < j)) return;
  float vji;
  if (rev >= 0) {
    vji = t5v[j * 5 + rev];
  } else {
    const float* g = G + (size_t)j * 768;
    const float* x = X + (size_t)i * 768;
    float a = 0.f;
#pragma unroll
    for (int u = 0; u < 12; ++u) a = fmaf(g[lane + 64 * u], x[lane + 64 * u], a);
#pragma unroll
    for (int d = 32; d; d >>= 1) a += __shfl_xor(a, d);
    float sa = 1.f / (1.f + expf(-ralpha[0]));
    vji = sa * Ae[(size_t)j * 8192 + i] + (1.f - sa) * fmaxf(a, 0.f);
  }
  if (lane == 0) {
    float vij = t5v[i * 5 + t];
    int p0 = off[i] + atomicAdd(&cursor[i], 1);
    ccol[p0] = j; cval[p0] = vij;
    int p1 = off[j] + atomicAdd(&cursor[j], 1);
    ccol[p1] = i; cval[p1] = vji;
  }
}

// M = D^-1 * (X[i] + sum val * X[j]) ; one block per row
__global__ __launch_bounds__(256) void gather_gcn(const float* __restrict__ X,
                                                  const int* __restrict__ off,
                                                  const int* __restrict__ ccol,
                                                  const float* __restrict__ cval,
                                                  float* __restrict__ M) {
  __shared__ float red[256];
  __shared__ float sdinv;
  int i = blockIdx.x, tid = threadIdx.x;
  int s0 = off[i], cnt = off[i + 1] - s0;
  float s = 0.f;
  for (int e = tid; e < cnt; e += 256) s += cval[s0 + e];
  red[tid] = s;
  __syncthreads();
  for (int d = 128; d; d >>= 1) {
    if (tid < d) red[tid] += red[tid + d];
    __syncthreads();
  }
  if (tid == 0) sdinv = 1.f / fmaxf(1.f + red[0], 1e-8f);
  __syncthreads();
  float dinv = sdinv;
  const float* xi = X + (size_t)i * 768;
  float a0 = xi[tid], a1 = xi[tid + 256], a2 = xi[tid + 512];
  for (int e = 0; e < cnt; ++e) {
    float v = cval[s0 + e];
    const float* xr = X + (size_t)ccol[s0 + e] * 768;
    a0 = fmaf(v, xr[tid], a0);
    a1 = fmaf(v, xr[tid + 256], a1);
    a2 = fmaf(v, xr[tid + 512], a2);
  }
  float* mi = M + (size_t)i * 768;
  mi[tid] = a0 * dinv; mi[tid + 256] = a1 * dinv; mi[tid + 512] = a2 * dinv;
}

__global__ __launch_bounds__(256) void final_head(const float* __restrict__ h2,
                                                  const float* __restrict__ W3,
                                                  const float* __restrict__ b3,
                                                  float* __restrict__ out) {
  int i = blockIdx.x * 4 + (threadIdx.x >> 6);
  int lane = threadIdx.x & 63;
  const float* r = h2 + (size_t)i * 256;
  float s = r[lane] * W3[lane] + r[lane + 64] * W3[lane + 64] +
            r[lane + 128] * W3[lane + 128] + r[lane + 192] * W3[lane + 192];
#pragma unroll
  for (int d = 32; d; d >>= 1) s += __shfl_xor(s, d);
  if (lane == 0) out[i] = s + b3[0];
}

extern "C" void kernel_launch(void* const* d_in, const int* in_sizes, int n_in,
                              void* d_out, int out_size, void* d_ws, size_t ws_size,
                              hipStream_t stream) {
  const float* X   = (const float*)d_in[0];
  const float* Ae  = (const float*)d_in[1];
  const float* Wg  = (const float*)d_in[2];
  const float* ra  = (const float*)d_in[3];
  const float* Wgc = (const float*)d_in[4];
  const float* bgc = (const float*)d_in[5];
  const float* W1  = (const float*)d_in[6];
  const float* b1  = (const float*)d_in[7];
  const float* W2  = (const float*)d_in[8];
  const float* b2  = (const float*)d_in[9];
  const float* W3  = (const float*)d_in[10];
  const float* b3  = (const float*)d_in[11];
  float* out = (float*)d_out;

  char* w = (char*)d_ws;
  size_t off_ = 0;
  auto take = [&](size_t n) -> void* {
    void* p = w + off_;
    off_ += (n + 255) & ~(size_t)255;
    return p;
  };
  float* G            = (float*)take((size_t)8192 * 768 * 4);          // 25.17 MB
  unsigned short* Xh  = (unsigned short*)take((size_t)8192 * 768 * 2); // 12.58
  unsigned short* Gh  = (unsigned short*)take((size_t)8192 * 768 * 2); // 12.58
  float* pv           = (float*)take((size_t)8192 * 320 * 4);          // 10.49
  int* pix            = (int*)take((size_t)8192 * 320 * 4);            // 10.49
  int* gidx           = (int*)take((size_t)8192 * 16 * 4);
  int* t5i            = (int*)take((size_t)8192 * 5 * 4);
  float* t5v          = (float*)take((size_t)8192 * 5 * 4);
  int* deg            = (int*)take((size_t)8192 * 4);
  int* offr           = (int*)take((size_t)8193 * 4);
  int* cur            = (int*)take((size_t)8192 * 4);
  int* ccol           = (int*)take((size_t)81920 * 4);
  float* cval         = (float*)take((size_t)81920 * 4);
  unsigned short* Wc2 = (unsigned short*)take((size_t)768 * 1536 * 2); // 2.36
  unsigned short* W12 = (unsigned short*)take((size_t)512 * 1536 * 2); // 1.57
  unsigned short* W22 = (unsigned short*)take((size_t)256 * 1024 * 2); // 0.52
  // total ~76 MB (< R1's proven 85.5 MB)

  // region reuse (stream-ordered):
  float* Mf  = (float*)Xh;   // Xh+Gh (25.17 MB, dead after s_topk): Mf -> Hf -> h1f
  float* Hf  = (float*)Xh;
  float* h1f = (float*)Xh;
  unsigned short* A2 = (unsigned short*)G;   // G (dead after edge_fill): activation planes
  float* h2f = (float*)pv;   // pv (10.49 MB, dead after merge16): h2 (8.39 MB)

  // 1. G = X @ Wg — fp32, k-ascending chain (selection-critical); bf16 copy fused
  sgemm_f32<<<dim3(128, 6), 256, 0, stream>>>(X, Wg, G, Gh, 768, 768);
  // 2. bf16 copy of X
  cvt_bf16<<<6144, 256, 0, stream>>>(X, Xh, 1572864);
  // 3. interleaved weight planes for MLP
  split_wt2<<<dim3(24, 24), 256, 0, stream>>>(Wgc, Wc2, 768, 768);
  split_wt2<<<dim3(24, 16), 256, 0, stream>>>(W1, W12, 768, 512);
  split_wt2<<<dim3(16, 8), 256, 0, stream>>>(W2, W22, 512, 256);

  // 4. fused S^T + lane-local top-5 partials (exact blend in refine5)
  s_topk<<<512, 512, 0, stream>>>(Gh, Xh, pv, pix);
  merge16<<<32, 256, 0, stream>>>(pv, pix, gidx);
  refine5<<<2048, 256, 0, stream>>>(G, X, Ae, gidx, ra, t5i, t5v);

  // 5. sparse symmetric A as CSR
  hipMemsetAsync(deg, 0, 8192 * 4, stream);
  hipMemsetAsync(cur, 0, 8192 * 4, stream);
  edge_deg<<<160, 256, 0, stream>>>(t5i, deg);
  scan8k<<<1, 256, 0, stream>>>(deg, offr);
  edge_fill<<<10240, 256, 0, stream>>>(t5i, t5v, G, X, Ae, ra, offr, cur, ccol, cval);

  // 6. M = A_norm @ X
  gather_gcn<<<8192, 256, 0, stream>>>(X, offr, ccol, cval, Mf);

  // 7. H = gelu(M @ Wgcn + bgc) — one split-bf16 pass, K=1536
  split2<<<6144, 256, 0, stream>>>(Mf, A2, 768, 1572864);
  gemm_bt<1><<<dim3(64, 6), 256, 0, stream>>>(A2, Wc2, bgc, Hf, 768, 1536);

  // 8. h1 = gelu(H @ W1 + b1)
  split2<<<6144, 256, 0, stream>>>(Hf, A2, 768, 1572864);
  gemm_bt<1><<<dim3(64, 4), 256, 0, stream>>>(A2, W12, b1, h1f, 512, 1536);

  // 9. h2 = gelu(h1 @ W2 + b2)
  split2<<<4096, 256, 0, stream>>>(h1f, A2, 512, 1048576);
  gemm_bt<1><<<dim3(64, 2), 256, 0, stream>>>(A2, W22, b2, h2f, 256, 1024);

  // 10. out = h2 @ W3 + b3
  final_head<<<2048, 256, 0, stream>>>(h2f, W3, b3, out);

  (void)in_sizes; (void)n_in; (void)out_size; (void)ws_size;
}

// Round 7
// 683.684 us; speedup vs baseline: 1.5156x; 1.0499x over previous
//
#include <hip/hip_runtime.h>
#include <math.h>

// SimpleGSLModel: B=8192, D=768, TOP_K=5
// R7: (a) s_topk XCD panel remap: p=bid&7 -> XCD owns an 8-i-tile panel (1.5MB, L2-resident)
//         x all 8 chunks; per-XCD working set ~3MB < 4MB L2. Cuts FETCH 450->~150MB.
//     (b) gemm_bt EPI=2: fused gelu + hi/lo bf16 split-plane write (drops 2 split2 passes
//         + f32 intermediates for H and h1).
//     Rest R6-verbatim (passed).

typedef __attribute__((ext_vector_type(8))) short short8v;
typedef __attribute__((ext_vector_type(4))) float f32x4;

__device__ __forceinline__ unsigned short f2bf(float f) {
  unsigned u = __float_as_uint(f);
  u += 0x7fffu + ((u >> 16) & 1u);   // RNE
  return (unsigned short)(u >> 16);
}
__device__ __forceinline__ float bf2f(unsigned short h) {
  return __uint_as_float(((unsigned)h) << 16);
}
__device__ __forceinline__ float gelu_f(float x) {
  return 0.5f * x * (1.f + erff(x * 0.7071067811865475f));
}
__device__ __forceinline__ void gload16(const void* g, void* l) {
  __builtin_amdgcn_global_load_lds(
      (const __attribute__((address_space(1))) unsigned int*)g,
      (__attribute__((address_space(3))) unsigned int*)l, 16, 0, 0);
}

// sorted-descending insert, static indexing, depth N
template <int N>
__device__ __forceinline__ void insN(float v, int j, float (&lv)[N], int (&li)[N]) {
#pragma unroll
  for (int p = N - 1; p >= 1; --p) {
    bool shiftv = v > lv[p - 1];
    bool here = (v > lv[p]) && !shiftv;
    float nv = shiftv ? lv[p - 1] : (here ? v : lv[p]);
    int ni = shiftv ? li[p - 1] : (here ? j : li[p]);
    lv[p] = nv; li[p] = ni;
  }
  if (v > lv[0]) { lv[0] = v; li[0] = j; }
}

__global__ __launch_bounds__(256) void cvt_bf16(const float* __restrict__ in,
                                                unsigned short* __restrict__ out, int n4) {
  int t = blockIdx.x * 256 + threadIdx.x;
  if (t >= n4) return;
  float4 f = ((const float4*)in)[t];
  ushort4 r;
  r.x = f2bf(f.x); r.y = f2bf(f.y); r.z = f2bf(f.z); r.w = f2bf(f.w);
  ((ushort4*)out)[t] = r;
}

// f32 [rows][K] -> bf16 hi/lo interleaved [rows][2K] (row = [hi(K) | lo(K)])
__global__ __launch_bounds__(256) void split2(const float* __restrict__ in,
                                              unsigned short* __restrict__ out,
                                              int K, int n4) {
  int t = blockIdx.x * 256 + threadIdx.x;
  if (t >= n4) return;
  int kq = K >> 2;
  int row = t / kq, c4 = t - row * kq;
  float4 f = ((const float4*)in)[t];
  ushort4 h, l;
  float x;
  x = f.x; h.x = f2bf(x); l.x = f2bf(x - bf2f(h.x));
  x = f.y; h.y = f2bf(x); l.y = f2bf(x - bf2f(h.y));
  x = f.z; h.z = f2bf(x); l.z = f2bf(x - bf2f(h.z));
  x = f.w; h.w = f2bf(x); l.w = f2bf(x - bf2f(h.w));
  *(ushort4*)(out + (size_t)row * 2 * K + c4 * 4) = h;
  *(ushort4*)(out + (size_t)row * 2 * K + K + c4 * 4) = l;
}

// W [K x N] f32 -> transposed hi/lo interleaved bf16 [N][2K]
__global__ __launch_bounds__(256) void split_wt2(const float* __restrict__ W,
                                                 unsigned short* __restrict__ t2,
                                                 int K, int N) {
  __shared__ float tile[32][33];
  int kb = blockIdx.x * 32, nb = blockIdx.y * 32;
  int tx = threadIdx.x & 31, ty = threadIdx.x >> 5;
#pragma unroll
  for (int p = 0; p < 4; ++p)
    tile[ty + p * 8][tx] = W[(size_t)(kb + ty + p * 8) * N + nb + tx];
  __syncthreads();
#pragma unroll
  for (int p = 0; p < 4; ++p) {
    int n = ty + p * 8;
    float x = tile[tx][n];
    unsigned short h = f2bf(x);
    unsigned short l = f2bf(x - bf2f(h));
    t2[(size_t)(nb + n) * (2 * K) + kb + tx] = h;
    t2[(size_t)(nb + n) * (2 * K) + K + kb + tx] = l;
  }
}

// -------- fp32 SGEMM for G. 64x128 tile; per-element fmaf chain (k ascending, single acc)
// -> bitwise-stable output (selection-critical). Fused bf16 copy of the result. --------
__global__ __launch_bounds__(256) void sgemm_f32(const float* __restrict__ A,
                                                 const float* __restrict__ Bm,
                                                 float* __restrict__ C,
                                                 unsigned short* __restrict__ Cbf,
                                                 int N, int K) {
  __shared__ float As[16][68];
  __shared__ float Bs[16][132];
  const int r0 = blockIdx.x * 64, c0 = blockIdx.y * 128;
  const int tid = threadIdx.x;
  const int tr = tid >> 4, tc = tid & 15;
  float acc[4][8];
#pragma unroll
  for (int i = 0; i < 4; ++i)
#pragma unroll
    for (int j = 0; j < 8; ++j) acc[i][j] = 0.f;

  for (int k0 = 0; k0 < K; k0 += 16) {
    {
      int row = tid >> 2, kq = tid & 3;
      float4 a4 = *(const float4*)(A + (size_t)(r0 + row) * K + k0 + kq * 4);
      As[kq * 4 + 0][row] = a4.x; As[kq * 4 + 1][row] = a4.y;
      As[kq * 4 + 2][row] = a4.z; As[kq * 4 + 3][row] = a4.w;
#pragma unroll
      for (int s = 0; s < 2; ++s) {
        int ch = tid + s * 256;
        int kk = ch >> 5, nq = ch & 31;
        *(float4*)&Bs[kk][nq * 4] = *(const float4*)(Bm + (size_t)(k0 + kk) * N + c0 + nq * 4);
      }
    }
    __syncthreads();
#pragma unroll
    for (int k = 0; k < 16; ++k) {
      float a[4], b[8];
      *(float4*)&a[0] = *(const float4*)&As[k][tr * 4];
      *(float4*)&b[0] = *(const float4*)&Bs[k][tc * 8];
      *(float4*)&b[4] = *(const float4*)&Bs[k][tc * 8 + 4];
#pragma unroll
      for (int i = 0; i < 4; ++i)
#pragma unroll
        for (int j = 0; j < 8; ++j) acc[i][j] = fmaf(a[i], b[j], acc[i][j]);
    }
    __syncthreads();
  }
#pragma unroll
  for (int i = 0; i < 4; ++i) {
    int r = r0 + tr * 4 + i;
#pragma unroll
    for (int jq = 0; jq < 2; ++jq) {
      *(float4*)(C + (size_t)r * N + c0 + tc * 8 + jq * 4) = *(float4*)&acc[i][jq * 4];
      ushort4 hb;
      hb.x = f2bf(acc[i][jq * 4 + 0]); hb.y = f2bf(acc[i][jq * 4 + 1]);
      hb.z = f2bf(acc[i][jq * 4 + 2]); hb.w = f2bf(acc[i][jq * 4 + 3]);
      *(ushort4*)(Cbf + (size_t)r * N + c0 + tc * 8 + jq * 4) = hb;
    }
  }
}

// ---------- bf16 MFMA GEMM, 128x128 tile, swizzled staging (conflict-free frag reads) ------
// EPI: 0 = raw f32 -> C ; 1 = gelu(x+bias) f32 -> C ; 2 = gelu(x+bias) hi/lo planes -> C2
template <int EPI>
__global__ __launch_bounds__(256) void gemm_bt(const unsigned short* __restrict__ A,
                                               const unsigned short* __restrict__ Bt,
                                               const float* __restrict__ bias,
                                               float* __restrict__ C,
                                               unsigned short* __restrict__ C2,
                                               int N, int K) {
  __shared__ __align__(16) unsigned short As[128 * 64];
  __shared__ __align__(16) unsigned short Bs[128 * 64];
  const int r0 = blockIdx.x * 128, c0 = blockIdx.y * 128;
  const int tid = threadIdx.x, lane = tid & 63, w = tid >> 6;
  const int wr = w >> 1, wc = w & 1;
  f32x4 acc[4][4];
  const f32x4 z4 = {0.f, 0.f, 0.f, 0.f};
#pragma unroll
  for (int i = 0; i < 4; ++i)
#pragma unroll
    for (int j = 0; j < 4; ++j) acc[i][j] = z4;

  const int srow = w * 32 + (lane >> 3);
  const int ksl = (lane & 7) ^ (lane >> 3);
  const unsigned short* aSrc = A + (size_t)(r0 + srow) * K + ksl * 8;
  const unsigned short* bSrc = Bt + (size_t)(c0 + srow) * K + ksl * 8;
  const int rsw = (lane & 7);

  for (int k0 = 0; k0 < K; k0 += 64) {
#pragma unroll
    for (int t = 0; t < 4; ++t) {
      gload16(aSrc + k0 + (size_t)t * 8 * K, (char*)As + (w * 32 + t * 8) * 128);
      gload16(bSrc + k0 + (size_t)t * 8 * K, (char*)Bs + (w * 32 + t * 8) * 128);
    }
    __syncthreads();
#pragma unroll
    for (int ks = 0; ks < 2; ++ks) {
      short8v af[4], bf[4];
      const int slot = ((ks * 4 + (lane >> 4)) ^ rsw) << 4;
#pragma unroll
      for (int f = 0; f < 4; ++f) {
        af[f] = *(const short8v*)((const char*)As + (wr * 64 + f * 16 + (lane & 15)) * 128 + slot);
        bf[f] = *(const short8v*)((const char*)Bs + (wc * 64 + f * 16 + (lane & 15)) * 128 + slot);
      }
#pragma unroll
      for (int fi = 0; fi < 4; ++fi)
#pragma unroll
        for (int fj = 0; fj < 4; ++fj)
          acc[fi][fj] = __builtin_amdgcn_mfma_f32_16x16x32_bf16(af[fi], bf[fj], acc[fi][fj], 0, 0, 0);
    }
    __syncthreads();
  }
#pragma unroll
  for (int fi = 0; fi < 4; ++fi)
#pragma unroll
    for (int fj = 0; fj < 4; ++fj) {
      int col = c0 + wc * 64 + fj * 16 + (lane & 15);
      int rowb = r0 + wr * 64 + fi * 16 + (lane >> 4) * 4;
#pragma unroll
      for (int r = 0; r < 4; ++r) {
        float x = acc[fi][fj][r];
        if constexpr (EPI == 0) {
          C[(size_t)(rowb + r) * N + col] = x;
        } else if constexpr (EPI == 1) {
          C[(size_t)(rowb + r) * N + col] = gelu_f(x + bias[col]);
        } else {
          float y = gelu_f(x + bias[col]);
          unsigned short h = f2bf(y);
          unsigned short l = f2bf(y - bf2f(h));
          C2[(size_t)(rowb + r) * 2 * N + col] = h;
          C2[(size_t)(rowb + r) * 2 * N + N + col] = l;
        }
      }
    }
}

// ---------- fused S^T tiles + lane-local top-5 (swapped operands: col=i, row=j) ----------
// XCD panel map: p=bid&7 (XCD), q=bid>>3; ib=p*8+(q&7); chunk=q>>3.
// Per XCD: 8 i-tiles (1.5MB Gh panel, L2-resident) x 8 chunks. 512 thr = 8 waves.
__global__ __launch_bounds__(512, 4) void s_topk(const unsigned short* __restrict__ Gh,
                                                 const unsigned short* __restrict__ Xh,
                                                 float* __restrict__ pv, int* __restrict__ pix) {
  __shared__ __align__(16) unsigned short As[128 * 64];   // j-tile (Xh rows) 16 KB
  __shared__ __align__(16) unsigned short Bs[128 * 64];   // i-tile (Gh rows) 16 KB
  const int bid = blockIdx.x;
  const int p = bid & 7, q = bid >> 3;
  const int r0 = (p * 8 + (q & 7)) * 128;
  const int chunk = q >> 3;
  const int tid = threadIdx.x, lane = tid & 63, w = tid >> 6;
  const int wr = w >> 2, wc = w & 3;
  float lv0[5], lv1[5]; int li0[5], li1[5];
#pragma unroll
  for (int q2 = 0; q2 < 5; ++q2) {
    lv0[q2] = -1e30f; li0[q2] = 0; lv1[q2] = -1e30f; li1[q2] = 0;
  }

  const int strow = tid >> 3, sslot = tid & 7;
  const int ksl = sslot ^ (strow & 7);
  const unsigned short* bSrc = Gh + (size_t)(r0 + strow) * 768 + ksl * 8;  // i rows, fixed
  char* aDst0 = (char*)As + strow * 128 + sslot * 16;
  char* bDst0 = (char*)Bs + strow * 128 + sslot * 16;
  const int rsw = lane & 7;

  for (int jt = 0; jt < 8; ++jt) {
    const int j0 = chunk * 1024 + jt * 128;
    const unsigned short* aSrc = Xh + (size_t)(j0 + strow) * 768 + ksl * 8;  // j rows
    f32x4 acc[4][2];
    const f32x4 z4 = {0.f, 0.f, 0.f, 0.f};
#pragma unroll
    for (int i = 0; i < 4; ++i) {
      acc[i][0] = z4; acc[i][1] = z4;
    }

    for (int k0 = 0; k0 < 768; k0 += 64) {
      gload16(aSrc + k0, aDst0);
      gload16(aSrc + k0 + (size_t)64 * 768, aDst0 + 64 * 128);
      gload16(bSrc + k0, bDst0);
      gload16(bSrc + k0 + (size_t)64 * 768, bDst0 + 64 * 128);
      __syncthreads();
#pragma unroll
      for (int ks = 0; ks < 2; ++ks) {
        short8v aj[4], bi[2];
        const int slot = ((ks * 4 + (lane >> 4)) ^ rsw) << 4;
#pragma unroll
        for (int f = 0; f < 4; ++f)
          aj[f] = *(const short8v*)((const char*)As + (wr * 64 + f * 16 + (lane & 15)) * 128 + slot);
#pragma unroll
        for (int f = 0; f < 2; ++f)
          bi[f] = *(const short8v*)((const char*)Bs + (wc * 32 + f * 16 + (lane & 15)) * 128 + slot);
#pragma unroll
        for (int fi = 0; fi < 4; ++fi) {
          acc[fi][0] = __builtin_amdgcn_mfma_f32_16x16x32_bf16(aj[fi], bi[0], acc[fi][0], 0, 0, 0);
          acc[fi][1] = __builtin_amdgcn_mfma_f32_16x16x32_bf16(aj[fi], bi[1], acc[fi][1], 0, 0, 0);
        }
      }
      __syncthreads();
    }
    // in-register scan: lane holds 16 j-values for each of 2 i's (acc dies here, no LDS)
    const int jb = j0 + wr * 64 + (lane >> 4) * 4;
#pragma unroll
    for (int fi = 0; fi < 4; ++fi)
#pragma unroll
      for (int r = 0; r < 4; ++r) {
        int jj = jb + fi * 16 + r;
        float v0 = acc[fi][0][r];
        if (v0 > lv0[4]) insN<5>(v0, jj, lv0, li0);
        float v1 = acc[fi][1][r];
        if (v1 > lv1[4]) insN<5>(v1, jj, lv1, li1);
      }
  }
  // write per-(i, chunk, slot) top-5; slot = wr*4 + lane-group
  const int slotw = wr * 4 + (lane >> 4);
  const int ib0 = r0 + wc * 32 + (lane & 15);
  size_t base0 = (((size_t)ib0 * 8 + chunk) * 8 + slotw) * 5;
#pragma unroll
  for (int q2 = 0; q2 < 5; ++q2) { pv[base0 + q2] = lv0[q2]; pix[base0 + q2] = li0[q2]; }
  size_t base1 = (((size_t)(ib0 + 16) * 8 + chunk) * 8 + slotw) * 5;
#pragma unroll
  for (int q2 = 0; q2 < 5; ++q2) { pv[base1 + q2] = lv1[q2]; pix[base1 + q2] = li1[q2]; }
}

// merge 8 chunks x 8 slots x 5 = 320 partial entries per row -> global top-16 candidates
__global__ __launch_bounds__(256) void merge16(const float* __restrict__ pv,
                                               const int* __restrict__ pix,
                                               int* __restrict__ gidx) {
  int row = blockIdx.x * 256 + threadIdx.x;
  float lv[16]; int li[16];
#pragma unroll
  for (int q = 0; q < 16; ++q) { lv[q] = -1e30f; li[q] = 0; }
  for (int ch = 0; ch < 8; ++ch)
#pragma unroll
    for (int sl = 0; sl < 8; ++sl) {
      size_t base = (((size_t)row * 8 + ch) * 8 + sl) * 5;
#pragma unroll
      for (int q = 0; q < 5; ++q) {
        float v = pv[base + q];
        if (v > lv[15]) insN<16>(v, pix[base + q], lv, li);
      }
    }
#pragma unroll
  for (int q = 0; q < 16; ++q) gidx[row * 16 + q] = li[q];
}

// exact f32 re-evaluation of 16 candidates (incl. Ae blend), exact top-5 (ties -> lower index)
__global__ __launch_bounds__(256) void refine5(const float* __restrict__ G,
                                               const float* __restrict__ X,
                                               const float* __restrict__ Ae,
                                               const int* __restrict__ gidx,
                                               const float* __restrict__ ralpha,
                                               int* __restrict__ t5i, float* __restrict__ t5v) {
  int i = blockIdx.x * 4 + (threadIdx.x >> 6);
  int lane = threadIdx.x & 63;
  int c = lane >> 2, s = lane & 3;
  float sa = 1.f / (1.f + expf(-ralpha[0]));
  int j = gidx[i * 16 + c];
  const float* g = G + (size_t)i * 768;
  const float* x = X + (size_t)j * 768;
  float a = 0.f;
#pragma unroll 8
  for (int t = 0; t < 192; ++t) a = fmaf(g[s + 4 * t], x[s + 4 * t], a);
  a += __shfl_xor(a, 1);
  a += __shfl_xor(a, 2);
  float v = sa * Ae[(size_t)i * 8192 + j] + (1.f - sa) * fmaxf(a, 0.f);
  float vs[16]; int js[16];
#pragma unroll
  for (int q = 0; q < 16; ++q) { vs[q] = __shfl(v, q * 4); js[q] = __shfl(j, q * 4); }
  if (lane == 0) {
    unsigned used = 0;
#pragma unroll
    for (int t = 0; t < 5; ++t) {
      float bv = -1e30f; int bj = 0; int bq = 0; bool any = false;
#pragma unroll
      for (int q = 0; q < 16; ++q) {
        bool ok = ((used >> q) & 1u) == 0u;
        bool better = ok && (!any || vs[q] > bv || (vs[q] == bv && js[q] < bj));
        bv = better ? vs[q] : bv; bj = better ? js[q] : bj; bq = better ? q : bq;
        any = any || better;
      }
      used |= (1u << bq);
      t5v[(size_t)i * 5 + t] = bv;
      t5i[(size_t)i * 5 + t] = bj;
    }
  }
}

// -------- symmetrized sparse-A construction (canonical-pair dedup) --------
__global__ void edge_deg(const int* __restrict__ t5i, int* __restrict__ deg) {
  int e = blockIdx.x * 256 + threadIdx.x;
  if (e >= 40960) return;
  int i = e / 5, t = e - i * 5;
  int j = t5i[i * 5 + t];
  if (j == i) return;
  bool rev = false;
#pragma unroll
  for (int u = 0; u < 5; ++u) rev = rev || (t5i[j * 5 + u] == i);
  if (!rev || i < j) { atomicAdd(&deg[i], 1); atomicAdd(&deg[j], 1); }
}

__global__ void scan8k(const int* __restrict__ deg, int* __restrict__ off) {
  __shared__ int sums[256];
  int tid = threadIdx.x;
  int base = tid * 32;
  int s = 0;
  for (int u = 0; u < 32; ++u) s += deg[base + u];
  sums[tid] = s;
  __syncthreads();
  for (int d = 1; d < 256; d <<= 1) {
    int v = (tid >= d) ? sums[tid - d] : 0;
    __syncthreads();
    sums[tid] += v;
    __syncthreads();
  }
  int run = tid ? sums[tid - 1] : 0;
  for (int u = 0; u < 32; ++u) { off[base + u] = run; run += deg[base + u]; }
  if (tid == 255) off[8192] = run;
}

__global__ __launch_bounds__(256) void edge_fill(const int* __restrict__ t5i,
                                                 const float* __restrict__ t5v,
                                                 const float* __restrict__ G,
                                                 const float* __restrict__ X,
                                                 const float* __restrict__ Ae,
                                                 const float* __restrict__ ralpha,
                                                 const int* __restrict__ off,
                                                 int* __restrict__ cursor,
                                                 int* __restrict__ ccol, float* __restrict__ cval) {
  int e = blockIdx.x * 4 + (threadIdx.x >> 6);
  if (e >= 40960) return;
  int lane = threadIdx.x & 63;
  int i = e / 5, t = e - i * 5;
  int j = t5i[i * 5 + t];
  if (j == i) return;
  int rev = -1;
#pragma unroll
  for (int u = 0; u < 5; ++u)
    if (t5i[j * 5 + u] == i) rev = u;
  if (!(rev < 0 || i < j)) return;
  float vji;
  if (rev >= 0) {
    vji = t5v[j * 5 + rev];
  } else {
    const float* g = G + (size_t)j * 768;
    const float* x = X + (size_t)i * 768;
    float a = 0.f;
#pragma unroll
    for (int u = 0; u < 12; ++u) a = fmaf(g[lane + 64 * u], x[lane + 64 * u], a);
#pragma unroll
    for (int d = 32; d; d >>= 1) a += __shfl_xor(a, d);
    float sa = 1.f / (1.f + expf(-ralpha[0]));
    vji = sa * Ae[(size_t)j * 8192 + i] + (1.f - sa) * fmaxf(a, 0.f);
  }
  if (lane == 0) {
    float vij = t5v[i * 5 + t];
    int p0 = off[i] + atomicAdd(&cursor[i], 1);
    ccol[p0] = j; cval[p0] = vij;
    int p1 = off[j] + atomicAdd(&cursor[j], 1);
    ccol[p1] = i; cval[p1] = vji;
  }
}

// M = D^-1 * (X[i] + sum val * X[j]) ; one block per row
__global__ __launch_bounds__(256) void gather_gcn(const float* __restrict__ X,
                                                  const int* __restrict__ off,
                                                  const int* __restrict__ ccol,
                                                  const float* __restrict__ cval,
                                                  float* __restrict__ M) {
  __shared__ float red[256];
  __shared__ float sdinv;
  int i = blockIdx.x, tid = threadIdx.x;
  int s0 = off[i], cnt = off[i + 1] - s0;
  float s = 0.f;
  for (int e = tid; e < cnt; e += 256) s += cval[s0 + e];
  red[tid] = s;
  __syncthreads();
  for (int d = 128; d; d >>= 1) {
    if (tid < d) red[tid] += red[tid + d];
    __syncthreads();
  }
  if (tid == 0) sdinv = 1.f / fmaxf(1.f + red[0], 1e-8f);
  __syncthreads();
  float dinv = sdinv;
  const float* xi = X + (size_t)i * 768;
  float a0 = xi[tid], a1 = xi[tid + 256], a2 = xi[tid + 512];
  for (int e = 0; e < cnt; ++e) {
    float v = cval[s0 + e];
    const float* xr = X + (size_t)ccol[s0 + e] * 768;
    a0 = fmaf(v, xr[tid], a0);
    a1 = fmaf(v, xr[tid + 256], a1);
    a2 = fmaf(v, xr[tid + 512], a2);
  }
  float* mi = M + (size_t)i * 768;
  mi[tid] = a0 * dinv; mi[tid + 256] = a1 * dinv; mi[tid + 512] = a2 * dinv;
}

__global__ __launch_bounds__(256) void final_head(const float* __restrict__ h2,
                                                  const float* __restrict__ W3,
                                                  const float* __restrict__ b3,
                                                  float* __restrict__ out) {
  int i = blockIdx.x * 4 + (threadIdx.x >> 6);
  int lane = threadIdx.x & 63;
  const float* r = h2 + (size_t)i * 256;
  float s = r[lane] * W3[lane] + r[lane + 64] * W3[lane + 64] +
            r[lane + 128] * W3[lane + 128] + r[lane + 192] * W3[lane + 192];
#pragma unroll
  for (int d = 32; d; d >>= 1) s += __shfl_xor(s, d);
  if (lane == 0) out[i] = s + b3[0];
}

extern "C" void kernel_launch(void* const* d_in, const int* in_sizes, int n_in,
                              void* d_out, int out_size, void* d_ws, size_t ws_size,
                              hipStream_t stream) {
  const float* X   = (const float*)d_in[0];
  const float* Ae  = (const float*)d_in[1];
  const float* Wg  = (const float*)d_in[2];
  const float* ra  = (const float*)d_in[3];
  const float* Wgc = (const float*)d_in[4];
  const float* bgc = (const float*)d_in[5];
  const float* W1  = (const float*)d_in[6];
  const float* b1  = (const float*)d_in[7];
  const float* W2  = (const float*)d_in[8];
  const float* b2  = (const float*)d_in[9];
  const float* W3  = (const float*)d_in[10];
  const float* b3  = (const float*)d_in[11];
  float* out = (float*)d_out;

  char* w = (char*)d_ws;
  size_t off_ = 0;
  auto take = [&](size_t n) -> void* {
    void* p = w + off_;
    off_ += (n + 255) & ~(size_t)255;
    return p;
  };
  float* G            = (float*)take((size_t)8192 * 768 * 4);          // 25.17 MB
  unsigned short* Xh  = (unsigned short*)take((size_t)8192 * 768 * 2); // 12.58
  unsigned short* Gh  = (unsigned short*)take((size_t)8192 * 768 * 2); // 12.58
  float* pv           = (float*)take((size_t)8192 * 320 * 4);          // 10.49
  int* pix            = (int*)take((size_t)8192 * 320 * 4);            // 10.49
  int* gidx           = (int*)take((size_t)8192 * 16 * 4);
  int* t5i            = (int*)take((size_t)8192 * 5 * 4);
  float* t5v          = (float*)take((size_t)8192 * 5 * 4);
  int* deg            = (int*)take((size_t)8192 * 4);
  int* offr           = (int*)take((size_t)8193 * 4);
  int* cur            = (int*)take((size_t)8192 * 4);
  int* ccol           = (int*)take((size_t)81920 * 4);
  float* cval         = (float*)take((size_t)81920 * 4);
  unsigned short* Wc2 = (unsigned short*)take((size_t)768 * 1536 * 2); // 2.36
  unsigned short* W12 = (unsigned short*)take((size_t)512 * 1536 * 2); // 1.57
  unsigned short* W22 = (unsigned short*)take((size_t)256 * 1024 * 2); // 0.52
  // total ~76 MB

  // region reuse (stream-ordered):
  // Xh+Gh region (25.17 MB contiguous): Mf (f32 8192x768) -> Hp2 (ushort 8192x1536 planes)
  float* Mf            = (float*)Xh;
  unsigned short* Hp2  = (unsigned short*)Xh;
  // G region (25.17 MB, dead after edge_fill): A2 planes -> h1p2 (ushort 8192x1024 planes)
  unsigned short* A2   = (unsigned short*)G;
  unsigned short* h1p2 = (unsigned short*)G;
  // pv region (10.49 MB, dead after merge16): h2 f32 (8.39 MB)
  float* h2f = (float*)pv;

  // 1. G = X @ Wg — fp32, k-ascending chain (selection-critical); bf16 copy fused
  sgemm_f32<<<dim3(128, 6), 256, 0, stream>>>(X, Wg, G, Gh, 768, 768);
  // 2. bf16 copy of X
  cvt_bf16<<<6144, 256, 0, stream>>>(X, Xh, 1572864);
  // 3. interleaved weight planes for MLP
  split_wt2<<<dim3(24, 24), 256, 0, stream>>>(Wgc, Wc2, 768, 768);
  split_wt2<<<dim3(24, 16), 256, 0, stream>>>(W1, W12, 768, 512);
  split_wt2<<<dim3(16, 8), 256, 0, stream>>>(W2, W22, 512, 256);

  // 4. fused S^T + lane-local top-5 partials (exact blend in refine5)
  s_topk<<<512, 512, 0, stream>>>(Gh, Xh, pv, pix);
  merge16<<<32, 256, 0, stream>>>(pv, pix, gidx);
  refine5<<<2048, 256, 0, stream>>>(G, X, Ae, gidx, ra, t5i, t5v);

  // 5. sparse symmetric A as CSR
  hipMemsetAsync(deg, 0, 8192 * 4, stream);
  hipMemsetAsync(cur, 0, 8192 * 4, stream);
  edge_deg<<<160, 256, 0, stream>>>(t5i, deg);
  scan8k<<<1, 256, 0, stream>>>(deg, offr);
  edge_fill<<<10240, 256, 0, stream>>>(t5i, t5v, G, X, Ae, ra, offr, cur, ccol, cval);

  // 6. M = A_norm @ X   (into Xh+Gh region)
  gather_gcn<<<8192, 256, 0, stream>>>(X, offr, ccol, cval, Mf);

  // 7. H planes = split(gelu(M @ Wgcn + bgc)) — split fused in epilogue
  split2<<<6144, 256, 0, stream>>>(Mf, A2, 768, 1572864);
  gemm_bt<2><<<dim3(64, 6), 256, 0, stream>>>(A2, Wc2, bgc, nullptr, Hp2, 768, 1536);

  // 8. h1 planes = split(gelu(H @ W1 + b1))
  gemm_bt<2><<<dim3(64, 4), 256, 0, stream>>>(Hp2, W12, b1, nullptr, h1p2, 512, 1536);

  // 9. h2 = gelu(h1 @ W2 + b2)  (f32, feeds final head)
  gemm_bt<1><<<dim3(64, 2), 256, 0, stream>>>(h1p2, W22, b2, h2f, nullptr, 256, 1024);

  // 10. out = h2 @ W3 + b3
  final_head<<<2048, 256, 0, stream>>>(h2f, W3, b3, out);

  (void)in_sizes; (void)n_in; (void)out_size; (void)ws_size;
}

// Round 8
// 661.128 us; speedup vs baseline: 1.5673x; 1.0341x over previous
//
#include <hip/hip_runtime.h>
#include <math.h>

// SimpleGSLModel: B=8192, D=768, TOP_K=5
// R8: 2-phase double-buffered pipelines (T3-minimum recipe: stage next -> compute cur ->
//     one barrier) in s_topk, sgemm_f32 (reg-staged; fmaf chain order preserved bitwise),
//     and gemm_bt. s_topk additionally prefetches next jt's first tile under the scan.
//     All arithmetic bit-identical to R7 (passed, absmax 3.9e-3).

typedef __attribute__((ext_vector_type(8))) short short8v;
typedef __attribute__((ext_vector_type(4))) float f32x4;

__device__ __forceinline__ unsigned short f2bf(float f) {
  unsigned u = __float_as_uint(f);
  u += 0x7fffu + ((u >> 16) & 1u);   // RNE
  return (unsigned short)(u >> 16);
}
__device__ __forceinline__ float bf2f(unsigned short h) {
  return __uint_as_float(((unsigned)h) << 16);
}
__device__ __forceinline__ float gelu_f(float x) {
  return 0.5f * x * (1.f + erff(x * 0.7071067811865475f));
}
__device__ __forceinline__ void gload16(const void* g, void* l) {
  __builtin_amdgcn_global_load_lds(
      (const __attribute__((address_space(1))) unsigned int*)g,
      (__attribute__((address_space(3))) unsigned int*)l, 16, 0, 0);
}

// sorted-descending insert, static indexing, depth N
template <int N>
__device__ __forceinline__ void insN(float v, int j, float (&lv)[N], int (&li)[N]) {
#pragma unroll
  for (int p = N - 1; p >= 1; --p) {
    bool shiftv = v > lv[p - 1];
    bool here = (v > lv[p]) && !shiftv;
    float nv = shiftv ? lv[p - 1] : (here ? v : lv[p]);
    int ni = shiftv ? li[p - 1] : (here ? j : li[p]);
    lv[p] = nv; li[p] = ni;
  }
  if (v > lv[0]) { lv[0] = v; li[0] = j; }
}

__global__ __launch_bounds__(256) void cvt_bf16(const float* __restrict__ in,
                                                unsigned short* __restrict__ out, int n4) {
  int t = blockIdx.x * 256 + threadIdx.x;
  if (t >= n4) return;
  float4 f = ((const float4*)in)[t];
  ushort4 r;
  r.x = f2bf(f.x); r.y = f2bf(f.y); r.z = f2bf(f.z); r.w = f2bf(f.w);
  ((ushort4*)out)[t] = r;
}

// f32 [rows][K] -> bf16 hi/lo interleaved [rows][2K] (row = [hi(K) | lo(K)])
__global__ __launch_bounds__(256) void split2(const float* __restrict__ in,
                                              unsigned short* __restrict__ out,
                                              int K, int n4) {
  int t = blockIdx.x * 256 + threadIdx.x;
  if (t >= n4) return;
  int kq = K >> 2;
  int row = t / kq, c4 = t - row * kq;
  float4 f = ((const float4*)in)[t];
  ushort4 h, l;
  float x;
  x = f.x; h.x = f2bf(x); l.x = f2bf(x - bf2f(h.x));
  x = f.y; h.y = f2bf(x); l.y = f2bf(x - bf2f(h.y));
  x = f.z; h.z = f2bf(x); l.z = f2bf(x - bf2f(h.z));
  x = f.w; h.w = f2bf(x); l.w = f2bf(x - bf2f(h.w));
  *(ushort4*)(out + (size_t)row * 2 * K + c4 * 4) = h;
  *(ushort4*)(out + (size_t)row * 2 * K + K + c4 * 4) = l;
}

// W [K x N] f32 -> transposed hi/lo interleaved bf16 [N][2K]
__global__ __launch_bounds__(256) void split_wt2(const float* __restrict__ W,
                                                 unsigned short* __restrict__ t2,
                                                 int K, int N) {
  __shared__ float tile[32][33];
  int kb = blockIdx.x * 32, nb = blockIdx.y * 32;
  int tx = threadIdx.x & 31, ty = threadIdx.x >> 5;
#pragma unroll
  for (int p = 0; p < 4; ++p)
    tile[ty + p * 8][tx] = W[(size_t)(kb + ty + p * 8) * N + nb + tx];
  __syncthreads();
#pragma unroll
  for (int p = 0; p < 4; ++p) {
    int n = ty + p * 8;
    float x = tile[tx][n];
    unsigned short h = f2bf(x);
    unsigned short l = f2bf(x - bf2f(h));
    t2[(size_t)(nb + n) * (2 * K) + kb + tx] = h;
    t2[(size_t)(nb + n) * (2 * K) + K + kb + tx] = l;
  }
}

// -------- fp32 SGEMM for G. 64x128 tile, reg-staged double buffer (1 barrier/step).
// Per-element fmaf chain (k ascending, single acc) identical -> bitwise-stable output.
// Fused bf16 copy of the result. --------
__global__ __launch_bounds__(256) void sgemm_f32(const float* __restrict__ A,
                                                 const float* __restrict__ Bm,
                                                 float* __restrict__ C,
                                                 unsigned short* __restrict__ Cbf,
                                                 int N, int K) {
  __shared__ float As[2][16][68];
  __shared__ float Bs[2][16][132];
  const int r0 = blockIdx.x * 64, c0 = blockIdx.y * 128;
  const int tid = threadIdx.x;
  const int tr = tid >> 4, tc = tid & 15;
  const int lrow = tid >> 2, lkq = tid & 3;
  const int kk0 = tid >> 5, nq = tid & 31;
  float acc[4][8];
#pragma unroll
  for (int i = 0; i < 4; ++i)
#pragma unroll
    for (int j = 0; j < 8; ++j) acc[i][j] = 0.f;

  const int nk = K >> 4;
  // prologue: load k0=0 -> regs -> LDS buf0
  float4 aR = *(const float4*)(A + (size_t)(r0 + lrow) * K + lkq * 4);
  float4 bR0 = *(const float4*)(Bm + (size_t)kk0 * N + c0 + nq * 4);
  float4 bR1 = *(const float4*)(Bm + (size_t)(kk0 + 8) * N + c0 + nq * 4);
  As[0][lkq * 4 + 0][lrow] = aR.x; As[0][lkq * 4 + 1][lrow] = aR.y;
  As[0][lkq * 4 + 2][lrow] = aR.z; As[0][lkq * 4 + 3][lrow] = aR.w;
  *(float4*)&Bs[0][kk0][nq * 4] = bR0;
  *(float4*)&Bs[0][kk0 + 8][nq * 4] = bR1;
  __syncthreads();

  int cur = 0;
  for (int t = 0; t < nk; ++t) {
    if (t < nk - 1) {
      int kn = (t + 1) * 16;
      aR = *(const float4*)(A + (size_t)(r0 + lrow) * K + kn + lkq * 4);
      bR0 = *(const float4*)(Bm + (size_t)(kn + kk0) * N + c0 + nq * 4);
      bR1 = *(const float4*)(Bm + (size_t)(kn + kk0 + 8) * N + c0 + nq * 4);
    }
#pragma unroll
    for (int k = 0; k < 16; ++k) {
      float a[4], b[8];
      *(float4*)&a[0] = *(const float4*)&As[cur][k][tr * 4];
      *(float4*)&b[0] = *(const float4*)&Bs[cur][k][tc * 8];
      *(float4*)&b[4] = *(const float4*)&Bs[cur][k][tc * 8 + 4];
#pragma unroll
      for (int i = 0; i < 4; ++i)
#pragma unroll
        for (int j = 0; j < 8; ++j) acc[i][j] = fmaf(a[i], b[j], acc[i][j]);
    }
    if (t < nk - 1) {
      int nxt = cur ^ 1;
      As[nxt][lkq * 4 + 0][lrow] = aR.x; As[nxt][lkq * 4 + 1][lrow] = aR.y;
      As[nxt][lkq * 4 + 2][lrow] = aR.z; As[nxt][lkq * 4 + 3][lrow] = aR.w;
      *(float4*)&Bs[nxt][kk0][nq * 4] = bR0;
      *(float4*)&Bs[nxt][kk0 + 8][nq * 4] = bR1;
    }
    __syncthreads();
    cur ^= 1;
  }
#pragma unroll
  for (int i = 0; i < 4; ++i) {
    int r = r0 + tr * 4 + i;
#pragma unroll
    for (int jq = 0; jq < 2; ++jq) {
      *(float4*)(C + (size_t)r * N + c0 + tc * 8 + jq * 4) = *(float4*)&acc[i][jq * 4];
      ushort4 hb;
      hb.x = f2bf(acc[i][jq * 4 + 0]); hb.y = f2bf(acc[i][jq * 4 + 1]);
      hb.z = f2bf(acc[i][jq * 4 + 2]); hb.w = f2bf(acc[i][jq * 4 + 3]);
      *(ushort4*)(Cbf + (size_t)r * N + c0 + tc * 8 + jq * 4) = hb;
    }
  }
}

// ---------- bf16 MFMA GEMM, 128x128 tile, swizzled staging, 2-phase dbuf ----------
// EPI: 0 = raw f32 -> C ; 1 = gelu(x+bias) f32 -> C ; 2 = gelu(x+bias) hi/lo planes -> C2
template <int EPI>
__global__ __launch_bounds__(256) void gemm_bt(const unsigned short* __restrict__ A,
                                               const unsigned short* __restrict__ Bt,
                                               const float* __restrict__ bias,
                                               float* __restrict__ C,
                                               unsigned short* __restrict__ C2,
                                               int N, int K) {
  __shared__ __align__(16) unsigned short As[2 * 128 * 64];
  __shared__ __align__(16) unsigned short Bs[2 * 128 * 64];
  const int r0 = blockIdx.x * 128, c0 = blockIdx.y * 128;
  const int tid = threadIdx.x, lane = tid & 63, w = tid >> 6;
  const int wr = w >> 1, wc = w & 1;
  f32x4 acc[4][4];
  const f32x4 z4 = {0.f, 0.f, 0.f, 0.f};
#pragma unroll
  for (int i = 0; i < 4; ++i)
#pragma unroll
    for (int j = 0; j < 4; ++j) acc[i][j] = z4;

  const int srow = w * 32 + (lane >> 3);
  const int ksl = (lane & 7) ^ (lane >> 3);
  const unsigned short* aSrc = A + (size_t)(r0 + srow) * K + ksl * 8;
  const unsigned short* bSrc = Bt + (size_t)(c0 + srow) * K + ksl * 8;
  const int rsw = (lane & 7);
  const int nk = K >> 6;

  // prologue: stage k0=0 into buf0
#pragma unroll
  for (int t4 = 0; t4 < 4; ++t4) {
    gload16(aSrc + (size_t)t4 * 8 * K, (char*)As + (w * 32 + t4 * 8) * 128);
    gload16(bSrc + (size_t)t4 * 8 * K, (char*)Bs + (w * 32 + t4 * 8) * 128);
  }
  __syncthreads();

  int cur = 0;
  for (int kt = 0; kt < nk; ++kt) {
    if (kt < nk - 1) {
      const int kn = (kt + 1) * 64;
      const int off = (cur ^ 1) * 16384;
#pragma unroll
      for (int t4 = 0; t4 < 4; ++t4) {
        gload16(aSrc + kn + (size_t)t4 * 8 * K, (char*)As + off + (w * 32 + t4 * 8) * 128);
        gload16(bSrc + kn + (size_t)t4 * 8 * K, (char*)Bs + off + (w * 32 + t4 * 8) * 128);
      }
    }
    const int cbase = cur * 16384;
#pragma unroll
    for (int ks = 0; ks < 2; ++ks) {
      short8v af[4], bf[4];
      const int slot = (((ks * 4 + (lane >> 4)) ^ rsw) << 4) + cbase;
#pragma unroll
      for (int f = 0; f < 4; ++f) {
        af[f] = *(const short8v*)((const char*)As + (wr * 64 + f * 16 + (lane & 15)) * 128 + slot);
        bf[f] = *(const short8v*)((const char*)Bs + (wc * 64 + f * 16 + (lane & 15)) * 128 + slot);
      }
#pragma unroll
      for (int fi = 0; fi < 4; ++fi)
#pragma unroll
        for (int fj = 0; fj < 4; ++fj)
          acc[fi][fj] = __builtin_amdgcn_mfma_f32_16x16x32_bf16(af[fi], bf[fj], acc[fi][fj], 0, 0, 0);
    }
    __syncthreads();
    cur ^= 1;
  }
#pragma unroll
  for (int fi = 0; fi < 4; ++fi)
#pragma unroll
    for (int fj = 0; fj < 4; ++fj) {
      int col = c0 + wc * 64 + fj * 16 + (lane & 15);
      int rowb = r0 + wr * 64 + fi * 16 + (lane >> 4) * 4;
#pragma unroll
      for (int r = 0; r < 4; ++r) {
        float x = acc[fi][fj][r];
        if constexpr (EPI == 0) {
          C[(size_t)(rowb + r) * N + col] = x;
        } else if constexpr (EPI == 1) {
          C[(size_t)(rowb + r) * N + col] = gelu_f(x + bias[col]);
        } else {
          float y = gelu_f(x + bias[col]);
          unsigned short h = f2bf(y);
          unsigned short l = f2bf(y - bf2f(h));
          C2[(size_t)(rowb + r) * 2 * N + col] = h;
          C2[(size_t)(rowb + r) * 2 * N + N + col] = l;
        }
      }
    }
}

// ---------- fused S^T tiles + lane-local top-5; 2-phase dbuf; scan hides next-jt stage ----
// XCD panel map: p=bid&7 (XCD), q=bid>>3; ib=p*8+(q&7); chunk=q>>3.
__global__ __launch_bounds__(512, 4) void s_topk(const unsigned short* __restrict__ Gh,
                                                 const unsigned short* __restrict__ Xh,
                                                 float* __restrict__ pv, int* __restrict__ pix) {
  __shared__ __align__(16) unsigned short As[2 * 128 * 64];   // j-tile dbuf 32 KB
  __shared__ __align__(16) unsigned short Bs[2 * 128 * 64];   // i-tile dbuf 32 KB
  const int bid = blockIdx.x;
  const int p = bid & 7, q = bid >> 3;
  const int r0 = (p * 8 + (q & 7)) * 128;
  const int chunk = q >> 3;
  const int tid = threadIdx.x, lane = tid & 63, w = tid >> 6;
  const int wr = w >> 2, wc = w & 3;
  float lv0[5], lv1[5]; int li0[5], li1[5];
#pragma unroll
  for (int q2 = 0; q2 < 5; ++q2) {
    lv0[q2] = -1e30f; li0[q2] = 0; lv1[q2] = -1e30f; li1[q2] = 0;
  }

  const int strow = tid >> 3, sslot = tid & 7;
  const int ksl = sslot ^ (strow & 7);
  const unsigned short* bSrc = Gh + (size_t)(r0 + strow) * 768 + ksl * 8;  // i rows, fixed
  char* aDst0 = (char*)As + strow * 128 + sslot * 16;
  char* bDst0 = (char*)Bs + strow * 128 + sslot * 16;
  const int rsw = lane & 7;

  // prologue: stage jt=0, k0=0 into buf0
  {
    const unsigned short* a0 = Xh + (size_t)(chunk * 1024 + strow) * 768 + ksl * 8;
    gload16(a0, aDst0);
    gload16(a0 + (size_t)64 * 768, aDst0 + 8192);
    gload16(bSrc, bDst0);
    gload16(bSrc + (size_t)64 * 768, bDst0 + 8192);
  }
  __syncthreads();

  int cur = 0;
  for (int jt = 0; jt < 8; ++jt) {
    const int j0 = chunk * 1024 + jt * 128;
    const unsigned short* aSrc = Xh + (size_t)(j0 + strow) * 768 + ksl * 8;
    f32x4 acc[4][2];
    const f32x4 z4 = {0.f, 0.f, 0.f, 0.f};
#pragma unroll
    for (int i = 0; i < 4; ++i) {
      acc[i][0] = z4; acc[i][1] = z4;
    }

    for (int t = 0; t < 12; ++t) {
      const int off = (cur ^ 1) * 16384;
      if (t < 11) {
        const int kn = (t + 1) * 64;
        gload16(aSrc + kn, aDst0 + off);
        gload16(aSrc + kn + (size_t)64 * 768, aDst0 + off + 8192);
        gload16(bSrc + kn, bDst0 + off);
        gload16(bSrc + kn + (size_t)64 * 768, bDst0 + off + 8192);
      } else if (jt < 7) {
        // prefetch next jt's k0=0 tile; its HBM latency hides under the scan below
        const unsigned short* aN = aSrc + (size_t)128 * 768;
        gload16(aN, aDst0 + off);
        gload16(aN + (size_t)64 * 768, aDst0 + off + 8192);
        gload16(bSrc, bDst0 + off);
        gload16(bSrc + (size_t)64 * 768, bDst0 + off + 8192);
      }
      const int cbase = cur * 16384;
#pragma unroll
      for (int ks = 0; ks < 2; ++ks) {
        short8v aj[4], bi[2];
        const int slot = (((ks * 4 + (lane >> 4)) ^ rsw) << 4) + cbase;
#pragma unroll
        for (int f = 0; f < 4; ++f)
          aj[f] = *(const short8v*)((const char*)As + (wr * 64 + f * 16 + (lane & 15)) * 128 + slot);
#pragma unroll
        for (int f = 0; f < 2; ++f)
          bi[f] = *(const short8v*)((const char*)Bs + (wc * 32 + f * 16 + (lane & 15)) * 128 + slot);
#pragma unroll
        for (int fi = 0; fi < 4; ++fi) {
          acc[fi][0] = __builtin_amdgcn_mfma_f32_16x16x32_bf16(aj[fi], bi[0], acc[fi][0], 0, 0, 0);
          acc[fi][1] = __builtin_amdgcn_mfma_f32_16x16x32_bf16(aj[fi], bi[1], acc[fi][1], 0, 0, 0);
        }
      }
      __syncthreads();
      cur ^= 1;
    }
    // in-register scan: lane holds 16 j-values for each of 2 i's
    const int jb = j0 + wr * 64 + (lane >> 4) * 4;
#pragma unroll
    for (int fi = 0; fi < 4; ++fi)
#pragma unroll
      for (int r = 0; r < 4; ++r) {
        int jj = jb + fi * 16 + r;
        float v0 = acc[fi][0][r];
        if (v0 > lv0[4]) insN<5>(v0, jj, lv0, li0);
        float v1 = acc[fi][1][r];
        if (v1 > lv1[4]) insN<5>(v1, jj, lv1, li1);
      }
  }
  // write per-(i, chunk, slot) top-5; slot = wr*4 + lane-group
  const int slotw = wr * 4 + (lane >> 4);
  const int ib0 = r0 + wc * 32 + (lane & 15);
  size_t base0 = (((size_t)ib0 * 8 + chunk) * 8 + slotw) * 5;
#pragma unroll
  for (int q2 = 0; q2 < 5; ++q2) { pv[base0 + q2] = lv0[q2]; pix[base0 + q2] = li0[q2]; }
  size_t base1 = (((size_t)(ib0 + 16) * 8 + chunk) * 8 + slotw) * 5;
#pragma unroll
  for (int q2 = 0; q2 < 5; ++q2) { pv[base1 + q2] = lv1[q2]; pix[base1 + q2] = li1[q2]; }
}

// merge 8 chunks x 8 slots x 5 = 320 partial entries per row -> global top-16 candidates
__global__ __launch_bounds__(256) void merge16(const float* __restrict__ pv,
                                               const int* __restrict__ pix,
                                               int* __restrict__ gidx) {
  int row = blockIdx.x * 256 + threadIdx.x;
  float lv[16]; int li[16];
#pragma unroll
  for (int q = 0; q < 16; ++q) { lv[q] = -1e30f; li[q] = 0; }
  for (int ch = 0; ch < 8; ++ch)
#pragma unroll
    for (int sl = 0; sl < 8; ++sl) {
      size_t base = (((size_t)row * 8 + ch) * 8 + sl) * 5;
#pragma unroll
      for (int q = 0; q < 5; ++q) {
        float v = pv[base + q];
        if (v > lv[15]) insN<16>(v, pix[base + q], lv, li);
      }
    }
#pragma unroll
  for (int q = 0; q < 16; ++q) gidx[row * 16 + q] = li[q];
}

// exact f32 re-evaluation of 16 candidates (incl. Ae blend), exact top-5 (ties -> lower index)
__global__ __launch_bounds__(256) void refine5(const float* __restrict__ G,
                                               const float* __restrict__ X,
                                               const float* __restrict__ Ae,
                                               const int* __restrict__ gidx,
                                               const float* __restrict__ ralpha,
                                               int* __restrict__ t5i, float* __restrict__ t5v) {
  int i = blockIdx.x * 4 + (threadIdx.x >> 6);
  int lane = threadIdx.x & 63;
  int c = lane >> 2, s = lane & 3;
  float sa = 1.f / (1.f + expf(-ralpha[0]));
  int j = gidx[i * 16 + c];
  const float* g = G + (size_t)i * 768;
  const float* x = X + (size_t)j * 768;
  float a = 0.f;
#pragma unroll 8
  for (int t = 0; t < 192; ++t) a = fmaf(g[s + 4 * t], x[s + 4 * t], a);
  a += __shfl_xor(a, 1);
  a += __shfl_xor(a, 2);
  float v = sa * Ae[(size_t)i * 8192 + j] + (1.f - sa) * fmaxf(a, 0.f);
  float vs[16]; int js[16];
#pragma unroll
  for (int q = 0; q < 16; ++q) { vs[q] = __shfl(v, q * 4); js[q] = __shfl(j, q * 4); }
  if (lane == 0) {
    unsigned used = 0;
#pragma unroll
    for (int t = 0; t < 5; ++t) {
      float bv = -1e30f; int bj = 0; int bq = 0; bool any = false;
#pragma unroll
      for (int q = 0; q < 16; ++q) {
        bool ok = ((used >> q) & 1u) == 0u;
        bool better = ok && (!any || vs[q] > bv || (vs[q] == bv && js[q] < bj));
        bv = better ? vs[q] : bv; bj = better ? js[q] : bj; bq = better ? q : bq;
        any = any || better;
      }
      used |= (1u << bq);
      t5v[(size_t)i * 5 + t] = bv;
      t5i[(size_t)i * 5 + t] = bj;
    }
  }
}

// -------- symmetrized sparse-A construction (canonical-pair dedup) --------
__global__ void edge_deg(const int* __restrict__ t5i, int* __restrict__ deg) {
  int e = blockIdx.x * 256 + threadIdx.x;
  if (e >= 40960) return;
  int i = e / 5, t = e - i * 5;
  int j = t5i[i * 5 + t];
  if (j == i) return;
  bool rev = false;
#pragma unroll
  for (int u = 0; u < 5; ++u) rev = rev || (t5i[j * 5 + u] == i);
  if (!rev || i < j) { atomicAdd(&deg[i], 1); atomicAdd(&deg[j], 1); }
}

__global__ void scan8k(const int* __restrict__ deg, int* __restrict__ off) {
  __shared__ int sums[256];
  int tid = threadIdx.x;
  int base = tid * 32;
  int s = 0;
  for (int u = 0; u < 32; ++u) s += deg[base + u];
  sums[tid] = s;
  __syncthreads();
  for (int d = 1; d < 256; d <<= 1) {
    int v = (tid >= d) ? sums[tid - d] : 0;
    __syncthreads();
    sums[tid] += v;
    __syncthreads();
  }
  int run = tid ? sums[tid - 1] : 0;
  for (int u = 0; u < 32; ++u) { off[base + u] = run; run += deg[base + u]; }
  if (tid == 255) off[8192] = run;
}

__global__ __launch_bounds__(256) void edge_fill(const int* __restrict__ t5i,
                                                 const float* __restrict__ t5v,
                                                 const float* __restrict__ G,
                                                 const float* __restrict__ X,
                                                 const float* __restrict__ Ae,
                                                 const float* __restrict__ ralpha,
                                                 const int* __restrict__ off,
                                                 int* __restrict__ cursor,
                                                 int* __restrict__ ccol, float* __restrict__ cval) {
  int e = blockIdx.x * 4 + (threadIdx.x >> 6);
  if (e >= 40960) return;
  int lane = threadIdx.x & 63;
  int i = e / 5, t = e - i * 5;
  int j = t5i[i * 5 + t];
  if (j == i) return;
  int rev = -1;
#pragma unroll
  for (int u = 0; u < 5; ++u)
    if (t5i[j * 5 + u] == i) rev = u;
  if (!(rev < 0 || i < j)) return;
  float vji;
  if (rev >= 0) {
    vji = t5v[j * 5 + rev];
  } else {
    const float* g = G + (size_t)j * 768;
    const float* x = X + (size_t)i * 768;
    float a = 0.f;
#pragma unroll
    for (int u = 0; u < 12; ++u) a = fmaf(g[lane + 64 * u], x[lane + 64 * u], a);
#pragma unroll
    for (int d = 32; d; d >>= 1) a += __shfl_xor(a, d);
    float sa = 1.f / (1.f + expf(-ralpha[0]));
    vji = sa * Ae[(size_t)j * 8192 + i] + (1.f - sa) * fmaxf(a, 0.f);
  }
  if (lane == 0) {
    float vij = t5v[i * 5 + t];
    int p0 = off[i] + atomicAdd(&cursor[i], 1);
    ccol[p0] = j; cval[p0] = vij;
    int p1 = off[j] + atomicAdd(&cursor[j], 1);
    ccol[p1] = i; cval[p1] = vji;
  }
}

// M = D^-1 * (X[i] + sum val * X[j]) ; one block per row
__global__ __launch_bounds__(256) void gather_gcn(const float* __restrict__ X,
                                                  const int* __restrict__ off,
                                                  const int* __restrict__ ccol,
                                                  const float* __restrict__ cval,
                                                  float* __restrict__ M) {
  __shared__ float red[256];
  __shared__ float sdinv;
  int i = blockIdx.x, tid = threadIdx.x;
  int s0 = off[i], cnt = off[i + 1] - s0;
  float s = 0.f;
  for (int e = tid; e < cnt; e += 256) s += cval[s0 + e];
  red[tid] = s;
  __syncthreads();
  for (int d = 128; d; d >>= 1) {
    if (tid < d) red[tid] += red[tid + d];
    __syncthreads();
  }
  if (tid == 0) sdinv = 1.f / fmaxf(1.f + red[0], 1e-8f);
  __syncthreads();
  float dinv = sdinv;
  const float* xi = X + (size_t)i * 768;
  float a0 = xi[tid], a1 = xi[tid + 256], a2 = xi[tid + 512];
  for (int e = 0; e < cnt; ++e) {
    float v = cval[s0 + e];
    const float* xr = X + (size_t)ccol[s0 + e] * 768;
    a0 = fmaf(v, xr[tid], a0);
    a1 = fmaf(v, xr[tid + 256], a1);
    a2 = fmaf(v, xr[tid + 512], a2);
  }
  float* mi = M + (size_t)i * 768;
  mi[tid] = a0 * dinv; mi[tid + 256] = a1 * dinv; mi[tid + 512] = a2 * dinv;
}

__global__ __launch_bounds__(256) void final_head(const float* __restrict__ h2,
                                                  const float* __restrict__ W3,
                                                  const float* __restrict__ b3,
                                                  float* __restrict__ out) {
  int i = blockIdx.x * 4 + (threadIdx.x >> 6);
  int lane = threadIdx.x & 63;
  const float* r = h2 + (size_t)i * 256;
  float s = r[lane] * W3[lane] + r[lane + 64] * W3[lane + 64] +
            r[lane + 128] * W3[lane + 128] + r[lane + 192] * W3[lane + 192];
#pragma unroll
  for (int d = 32; d; d >>= 1) s += __shfl_xor(s, d);
  if (lane == 0) out[i] = s + b3[0];
}

extern "C" void kernel_launch(void* const* d_in, const int* in_sizes, int n_in,
                              void* d_out, int out_size, void* d_ws, size_t ws_size,
                              hipStream_t stream) {
  const float* X   = (const float*)d_in[0];
  const float* Ae  = (const float*)d_in[1];
  const float* Wg  = (const float*)d_in[2];
  const float* ra  = (const float*)d_in[3];
  const float* Wgc = (const float*)d_in[4];
  const float* bgc = (const float*)d_in[5];
  const float* W1  = (const float*)d_in[6];
  const float* b1  = (const float*)d_in[7];
  const float* W2  = (const float*)d_in[8];
  const float* b2  = (const float*)d_in[9];
  const float* W3  = (const float*)d_in[10];
  const float* b3  = (const float*)d_in[11];
  float* out = (float*)d_out;

  char* w = (char*)d_ws;
  size_t off_ = 0;
  auto take = [&](size_t n) -> void* {
    void* p = w + off_;
    off_ += (n + 255) & ~(size_t)255;
    return p;
  };
  float* G            = (float*)take((size_t)8192 * 768 * 4);          // 25.17 MB
  unsigned short* Xh  = (unsigned short*)take((size_t)8192 * 768 * 2); // 12.58
  unsigned short* Gh  = (unsigned short*)take((size_t)8192 * 768 * 2); // 12.58
  float* pv           = (float*)take((size_t)8192 * 320 * 4);          // 10.49
  int* pix            = (int*)take((size_t)8192 * 320 * 4);            // 10.49
  int* gidx           = (int*)take((size_t)8192 * 16 * 4);
  int* t5i            = (int*)take((size_t)8192 * 5 * 4);
  float* t5v          = (float*)take((size_t)8192 * 5 * 4);
  int* deg            = (int*)take((size_t)8192 * 4);
  int* offr           = (int*)take((size_t)8193 * 4);
  int* cur            = (int*)take((size_t)8192 * 4);
  int* ccol           = (int*)take((size_t)81920 * 4);
  float* cval         = (float*)take((size_t)81920 * 4);
  unsigned short* Wc2 = (unsigned short*)take((size_t)768 * 1536 * 2); // 2.36
  unsigned short* W12 = (unsigned short*)take((size_t)512 * 1536 * 2); // 1.57
  unsigned short* W22 = (unsigned short*)take((size_t)256 * 1024 * 2); // 0.52
  // total ~76 MB

  // region reuse (stream-ordered):
  float* Mf            = (float*)Xh;            // Xh+Gh: Mf -> Hp2
  unsigned short* Hp2  = (unsigned short*)Xh;
  unsigned short* A2   = (unsigned short*)G;    // G (dead after edge_fill): A2 -> h1p2
  unsigned short* h1p2 = (unsigned short*)G;
  float* h2f = (float*)pv;                      // pv (dead after merge16): h2

  // 1. G = X @ Wg — fp32, k-ascending chain (selection-critical); bf16 copy fused
  sgemm_f32<<<dim3(128, 6), 256, 0, stream>>>(X, Wg, G, Gh, 768, 768);
  // 2. bf16 copy of X
  cvt_bf16<<<6144, 256, 0, stream>>>(X, Xh, 1572864);
  // 3. interleaved weight planes for MLP
  split_wt2<<<dim3(24, 24), 256, 0, stream>>>(Wgc, Wc2, 768, 768);
  split_wt2<<<dim3(24, 16), 256, 0, stream>>>(W1, W12, 768, 512);
  split_wt2<<<dim3(16, 8), 256, 0, stream>>>(W2, W22, 512, 256);

  // 4. fused S^T + lane-local top-5 partials (exact blend in refine5)
  s_topk<<<512, 512, 0, stream>>>(Gh, Xh, pv, pix);
  merge16<<<32, 256, 0, stream>>>(pv, pix, gidx);
  refine5<<<2048, 256, 0, stream>>>(G, X, Ae, gidx, ra, t5i, t5v);

  // 5. sparse symmetric A as CSR
  hipMemsetAsync(deg, 0, 8192 * 4, stream);
  hipMemsetAsync(cur, 0, 8192 * 4, stream);
  edge_deg<<<160, 256, 0, stream>>>(t5i, deg);
  scan8k<<<1, 256, 0, stream>>>(deg, offr);
  edge_fill<<<10240, 256, 0, stream>>>(t5i, t5v, G, X, Ae, ra, offr, cur, ccol, cval);

  // 6. M = A_norm @ X
  gather_gcn<<<8192, 256, 0, stream>>>(X, offr, ccol, cval, Mf);

  // 7. H planes = split(gelu(M @ Wgcn + bgc))
  split2<<<6144, 256, 0, stream>>>(Mf, A2, 768, 1572864);
  gemm_bt<2><<<dim3(64, 6), 256, 0, stream>>>(A2, Wc2, bgc, nullptr, Hp2, 768, 1536);

  // 8. h1 planes = split(gelu(H @ W1 + b1))
  gemm_bt<2><<<dim3(64, 4), 256, 0, stream>>>(Hp2, W12, b1, nullptr, h1p2, 512, 1536);

  // 9. h2 = gelu(h1 @ W2 + b2)
  gemm_bt<1><<<dim3(64, 2), 256, 0, stream>>>(h1p2, W22, b2, h2f, nullptr, 256, 1024);

  // 10. out = h2 @ W3 + b3
  final_head<<<2048, 256, 0, stream>>>(h2f, W3, b3, out);

  (void)in_sizes; (void)n_in; (void)out_size; (void)ws_size;
}